// Round 5
// baseline (338.198 us; speedup 1.0000x reference)
//
#include <hip/hip_runtime.h>
#include <hip/hip_bf16.h>
#include <stdint.h>

typedef unsigned short u16;
typedef __bf16 bf16_t;
typedef bf16_t bf16x8 __attribute__((ext_vector_type(8)));
typedef float f32x4 __attribute__((ext_vector_type(4)));

#define DEV static __device__ __forceinline__

// ---------- helpers ----------
DEV u16 f2b(float f) {
    __hip_bfloat16 h = __float2bfloat16(f);
    return __builtin_bit_cast(u16, h);
}

DEV bf16x8 ld_frag(const u16* p) {
    uint4 u = *reinterpret_cast<const uint4*>(p);
    return __builtin_bit_cast(bf16x8, u);
}

// exact-GELU via tanh identity (max abs err ~3e-4 vs erf form; margin is 0.07)
DEV float gelu(float v) {
    float y = 0.79788456080286536f * (v + 0.044715f * v * v * v);
    float e = __expf(-2.f * fabsf(y));
    float th = (1.f - e) / (1.f + e);
    th = copysignf(th, y);
    return 0.5f * v * (1.f + th);
}

// async global->LDS, 16B per lane. LDS dest wave-uniform base + lane*16; global src per-lane.
DEV void gl_lds16(const u16* g, u16* l) {
    __builtin_amdgcn_global_load_lds(
        (const __attribute__((address_space(1))) void*)(uintptr_t)g,
        (__attribute__((address_space(3))) void*)(unsigned int)(uintptr_t)l,
        16, 0, 0);
}

// ---------- weight fp32 -> bf16 conversion (16 regions, one launch) ----------
struct ConvEnt { const float* s; u16* d; int n; };
struct ConvArgs { ConvEnt e[16]; };

__global__ __launch_bounds__(256) void k_conv(ConvArgs a) {
    const ConvEnt en = a.e[blockIdx.y];
    int i = (blockIdx.x * 256 + threadIdx.x) * 4;
    if (i >= en.n) return;
    const float4 f = *reinterpret_cast<const float4*>(en.s + i);
    unsigned r0 = (unsigned)f2b(f.x) | ((unsigned)f2b(f.y) << 16);
    unsigned r1 = (unsigned)f2b(f.z) | ((unsigned)f2b(f.w) << 16);
    uint2 rr; rr.x = r0; rr.y = r1;
    *reinterpret_cast<uint2*>(en.d + i) = rr;
}

// ---------- fused-bias concat: 8 copies of 512 floats ----------
struct CpyEnt { const float* s; float* d; };
struct CpyArgs { CpyEnt e[8]; };

__global__ __launch_bounds__(256) void k_cpyf(CpyArgs a) {
    const CpyEnt en = a.e[blockIdx.y];
    int i = blockIdx.x * 256 + threadIdx.x;
    en.d[i] = en.s[i];
}

// ---------- merged transpose in: (B,D,L)->(B,L,D) for LL and LH ----------
__global__ __launch_bounds__(256) void k_tin(const float* __restrict__ LL, const float* __restrict__ LH,
                                             float* __restrict__ llf, u16* __restrict__ llb,
                                             float* __restrict__ lhf, u16* __restrict__ lhb) {
    __shared__ float t[32][33];
    int z = blockIdx.z, b = z & 3;
    const float* in = (z < 4) ? LL : LH;
    float* of = (z < 4) ? llf : lhf;
    u16* ob = (z < 4) ? llb : lhb;
    int l0 = blockIdx.x * 32, d0 = blockIdx.y * 32;
    int tx = threadIdx.x, ty = threadIdx.y;  // (32,8)
#pragma unroll
    for (int j = 0; j < 4; ++j) {
        int d = d0 + ty + j * 8;
        t[ty + j * 8][tx] = in[((size_t)b * 512 + d) * 1024 + l0 + tx];
    }
    __syncthreads();
#pragma unroll
    for (int j = 0; j < 4; ++j) {
        int l = l0 + ty + j * 8;
        float v = t[tx][ty + j * 8];
        size_t o = ((size_t)b * 1024 + l) * 512 + d0 + tx;
        of[o] = v;
        ob[o] = f2b(v);
    }
}

// ---------- merged transpose out: (B,L,D)->(B,D,L) for both outputs ----------
__global__ __launch_bounds__(256) void k_tout(const float* __restrict__ y0, const float* __restrict__ y1,
                                              float* __restrict__ out) {
    __shared__ float t[32][33];
    int z = blockIdx.z, b = z & 3;
    const float* in = (z < 4) ? y0 : y1;
    float* o = out + ((z < 4) ? 0 : (size_t)4096 * 512);
    int l0 = blockIdx.x * 32, d0 = blockIdx.y * 32;
    int tx = threadIdx.x, ty = threadIdx.y;
#pragma unroll
    for (int j = 0; j < 4; ++j) {
        int l = l0 + ty + j * 8;
        t[ty + j * 8][tx] = in[((size_t)b * 1024 + l) * 512 + d0 + tx];
    }
    __syncthreads();
#pragma unroll
    for (int j = 0; j < 4; ++j) {
        int d = d0 + ty + j * 8;
        o[((size_t)b * 512 + d) * 1024 + l0 + tx] = t[tx][ty + j * 8];
    }
}

// ---------- energy mask ----------
__global__ __launch_bounds__(256) void k_mask(const float* __restrict__ lh_s,
                                              const float* __restrict__ raw_tau,
                                              float* __restrict__ kbias) {
    int row = blockIdx.x * 4 + (threadIdx.x >> 6);
    int lane = threadIdx.x & 63;
    const float* p = lh_s + (size_t)row * 512 + lane * 8;
    float s = 0.f;
#pragma unroll
    for (int j = 0; j < 8; ++j) s += fabsf(p[j]);
#pragma unroll
    for (int m = 32; m >= 1; m >>= 1) s += __shfl_xor(s, m, 64);
    float tau = 1.f / (1.f + expf(-raw_tau[0]));
    if (lane == 0) kbias[row] = (s * (1.f / 512.f) > tau) ? 0.f : -3.0e38f;
}

// ---------- LayerNorm over D=512 of (a + b [+ c]) ----------
__global__ __launch_bounds__(256) void k_ln(const float* __restrict__ a, const float* __restrict__ b,
                                            const float* __restrict__ c, const float* __restrict__ w,
                                            const float* __restrict__ bi,
                                            float* __restrict__ of, u16* __restrict__ ob) {
    int row = blockIdx.x * 4 + (threadIdx.x >> 6);
    int lane = threadIdx.x & 63;
    size_t base = (size_t)row * 512 + lane * 8;
    float x[8];
#pragma unroll
    for (int j = 0; j < 8; ++j) {
        float v = a[base + j] + b[base + j];
        if (c) v += c[base + j];
        x[j] = v;
    }
    float s = 0.f, s2 = 0.f;
#pragma unroll
    for (int j = 0; j < 8; ++j) { s += x[j]; s2 += x[j] * x[j]; }
#pragma unroll
    for (int m = 32; m >= 1; m >>= 1) { s += __shfl_xor(s, m, 64); s2 += __shfl_xor(s2, m, 64); }
    float mean = s * (1.f / 512.f);
    float var = s2 * (1.f / 512.f) - mean * mean;
    float rs = rsqrtf(var + 1e-5f);
#pragma unroll
    for (int j = 0; j < 8; ++j) {
        float y = (x[j] - mean) * rs * w[lane * 8 + j] + bi[lane * 8 + j];
        of[base + j] = y;
        ob[base + j] = f2b(y);
    }
}

// ---------- batched bf16 MFMA GEMM (multi-descriptor, XCD-chunked flat grid) ----------
// single-buffered m97 2-barrier structure: 32KB LDS @128x128 -> 5 blocks/CU
struct GDesc {
    const u16* A; const u16* W; const float* bias; const float* res;
    float* Cf; u16* Cb; u16* Qp; u16* Kp; u16* Vt;
    int kB, vB;
    int N, K;
    int gelu, outf, outb, isres, pack;
    int blk0;
};
struct GArgs { GDesc d[3]; int nd; int total; };

template <int BM, int BN>
__global__ __launch_bounds__(256) void k_bgemm(GArgs ga) {
    constexpr int BK = 64;
    __shared__ alignas(16) u16 Al[BM * BK];
    __shared__ alignas(16) u16 Wl[BN * BK];
    // bijective XCD-chunk swizzle (m204): XCD x owns a contiguous chunk of the grid
    const int nwg = ga.total, orig = blockIdx.x;
    const int xcd = orig & 7, lin = orig >> 3;
    const int q = nwg >> 3, r = nwg & 7;
    const int bid = (xcd < r ? xcd * (q + 1) : r * (q + 1) + (xcd - r) * q) + lin;

    int di = 0;
    if (ga.nd > 1 && bid >= ga.d[1].blk0) di = 1;
    if (ga.nd > 2 && bid >= ga.d[2].blk0) di = 2;
    GDesc g;
    if (di == 0) g = ga.d[0];
    else if (di == 1) g = ga.d[1];
    else g = ga.d[2];
    const int rel = bid - g.blk0;
    const int K = g.K, N = g.N;
    const int nny = N / BN;  // n-fastest decode: XCD chunk spans few m-rows, all n
    const int m0 = (rel / nny) * BM, n0 = (rel % nny) * BN;

    const int t = threadIdx.x, w = t >> 6, l = t & 63;
    constexpr int FM = BM / 32, FN = BN / 32;
    const int wr = w >> 1, wc = w & 1;
    const int lq = l & 15, lg = l >> 4;
    f32x4 acc[FM][FN] = {};

    const int srow = l >> 3, scol = (l & 7) * 8;
    auto stage = [&](int kcol) {
#pragma unroll
        for (int i = 0; i < BM / 32; ++i)
            gl_lds16(g.A + (size_t)(m0 + i * 32 + w * 8 + srow) * K + kcol + scol, &Al[(i * 32 + w * 8) * BK]);
#pragma unroll
        for (int i = 0; i < BN / 32; ++i)
            gl_lds16(g.W + (size_t)(n0 + i * 32 + w * 8 + srow) * K + kcol + scol, &Wl[(i * 32 + w * 8) * BK]);
    };

    const int KT = K / BK;
    for (int kt = 0; kt < KT; ++kt) {
        stage(kt * BK);
        __syncthreads();  // drains vmcnt -> LDS tile ready
#pragma unroll
        for (int s = 0; s < 2; ++s) {
            bf16x8 af[FM], bw[FN];
#pragma unroll
            for (int i = 0; i < FM; ++i)
                af[i] = ld_frag(&Al[(wr * (BM / 2) + i * 16 + lq) * BK + s * 32 + lg * 8]);
#pragma unroll
            for (int j = 0; j < FN; ++j)
                bw[j] = ld_frag(&Wl[(wc * (BN / 2) + j * 16 + lq) * BK + s * 32 + lg * 8]);
#pragma unroll
            for (int i = 0; i < FM; ++i)
#pragma unroll
                for (int j = 0; j < FN; ++j)
                    acc[i][j] = __builtin_amdgcn_mfma_f32_16x16x32_bf16(af[i], bw[j], acc[i][j], 0, 0, 0);
        }
        __syncthreads();  // all reads done before next stage overwrites
    }
#pragma unroll
    for (int i = 0; i < FM; ++i) {
#pragma unroll
        for (int j = 0; j < FN; ++j) {
            const int n = n0 + wc * (BN / 2) + j * 16 + lq;
            const float bn = g.bias[n];
#pragma unroll
            for (int r2 = 0; r2 < 4; ++r2) {
                const int m = m0 + wr * (BM / 2) + i * 16 + lg * 4 + r2;
                float v = acc[i][j][r2] + bn;
                if (g.gelu) v = gelu(v);
                if (g.pack) {
                    const int bb = m >> 10, ll_ = m & 1023;
                    if (n >= g.vB) {
                        const int d = n - g.vB;
                        g.Vt[((size_t)(bb * 8 + (d >> 6)) * 64 + (d & 63)) * 1024 + ll_] = f2b(v);
                    } else if (n >= g.kB) {
                        const int d = n - g.kB;
                        g.Kp[((size_t)(bb * 8 + (d >> 6)) * 1024 + ll_) * 64 + (d & 63)] = f2b(v);
                    } else {
                        g.Qp[((size_t)(bb * 8 + (n >> 6)) * 1024 + ll_) * 64 + (n & 63)] = f2b(v * 0.125f);
                    }
                } else {
                    size_t o = (size_t)m * N + n;
                    if (g.isres) v += g.res[o];
                    if (g.outf) g.Cf[o] = v;
                    if (g.outb) g.Cb[o] = f2b(v);
                }
            }
        }
    }
}

// ---------- flash attention: 2-phase dbuf, no-max softmax, deferred denom ----------
__global__ __launch_bounds__(256) void k_attn(const u16* __restrict__ Qp, const u16* __restrict__ Kp,
                                              const u16* __restrict__ Vtp, u16* __restrict__ O,
                                              const float* __restrict__ kbias) {
    constexpr int L = 1024;
    __shared__ alignas(16) u16 Kl[2][64 * 64];
    __shared__ alignas(16) u16 Vl[2][64 * 64];
    __shared__ alignas(16) u16 Pl[64 * 72];
    const int t = threadIdx.x, w = t >> 6, l = t & 63;
    const int q0 = blockIdx.x * 64;
    const int h = blockIdx.y, bz = blockIdx.z, bh = bz * 8 + h;
    const int lq = l & 15, lg = l >> 4;
    const float* kb = (kbias != nullptr && bz >= 4) ? (kbias + (size_t)(bz - 4) * L) : nullptr;

    bf16x8 qa0, qa1;
    {
        const u16* qp = Qp + ((size_t)bh * L + q0 + w * 16 + lq) * 64 + lg * 8;
        qa0 = ld_frag(qp);
        qa1 = ld_frag(qp + 32);
    }

    const int r0 = w * 16 + (l >> 3), r1 = r0 + 8, c = l & 7;
    const u16* Ksrc0 = Kp + (size_t)bh * L * 64 + (size_t)r0 * 64 + ((c ^ (r0 & 7)) * 8);
    const u16* Ksrc1 = Kp + (size_t)bh * L * 64 + (size_t)r1 * 64 + ((c ^ (r1 & 7)) * 8);
    const u16* Vsrc0 = Vtp + (size_t)bh * 64 * L + (size_t)r0 * L + ((c ^ (r0 & 7)) * 8);
    const u16* Vsrc1 = Vtp + (size_t)bh * 64 * L + (size_t)r1 * L + ((c ^ (r1 & 7)) * 8);

    auto stage = [&](int k0, int buf) {
        gl_lds16(Ksrc0 + (size_t)k0 * 64, &Kl[buf][(w * 16) * 64]);
        gl_lds16(Ksrc1 + (size_t)k0 * 64, &Kl[buf][(w * 16 + 8) * 64]);
        gl_lds16(Vsrc0 + k0, &Vl[buf][(w * 16) * 64]);
        gl_lds16(Vsrc1 + k0, &Vl[buf][(w * 16 + 8) * 64]);
    };

    int addrA[4][2];
#pragma unroll
    for (int f = 0; f < 4; ++f) {
        int row = f * 16 + lq;
#pragma unroll
        for (int s = 0; s < 2; ++s) addrA[f][s] = row * 64 + (((s * 4 + lg) ^ (row & 7)) * 8);
    }
    const int paddr0 = (w * 16 + lq) * 72 + lg * 8;

    f32x4 oacc[4] = {};
    float lrow[4] = {0.f, 0.f, 0.f, 0.f};

    stage(0, 0);
    for (int kt = 0; kt < 16; ++kt) {
        const int cur = kt & 1;
        __syncthreads();
        if (kt + 1 < 16) stage((kt + 1) * 64, cur ^ 1);

        f32x4 sc4[4];
#pragma unroll
        for (int f = 0; f < 4; ++f) {
            f32x4 a = {};
            a = __builtin_amdgcn_mfma_f32_16x16x32_bf16(qa0, ld_frag(&Kl[cur][addrA[f][0]]), a, 0, 0, 0);
            a = __builtin_amdgcn_mfma_f32_16x16x32_bf16(qa1, ld_frag(&Kl[cur][addrA[f][1]]), a, 0, 0, 0);
            sc4[f] = a;
        }
#pragma unroll
        for (int f = 0; f < 4; ++f) {
            float bv = kb ? kb[kt * 64 + f * 16 + lq] : 0.f;
#pragma unroll
            for (int r = 0; r < 4; ++r) {
                float pv = __expf(sc4[f][r] + bv);
                lrow[r] += pv;
                Pl[(w * 16 + lg * 4 + r) * 72 + f * 16 + lq] = f2b(pv);
            }
        }
        bf16x8 pa0 = ld_frag(&Pl[paddr0]);
        bf16x8 pa1 = ld_frag(&Pl[paddr0 + 32]);
#pragma unroll
        for (int db = 0; db < 4; ++db) {
            oacc[db] = __builtin_amdgcn_mfma_f32_16x16x32_bf16(pa0, ld_frag(&Vl[cur][addrA[db][0]]), oacc[db], 0, 0, 0);
            oacc[db] = __builtin_amdgcn_mfma_f32_16x16x32_bf16(pa1, ld_frag(&Vl[cur][addrA[db][1]]), oacc[db], 0, 0, 0);
        }
    }
#pragma unroll
    for (int r = 0; r < 4; ++r) {
        float v = lrow[r];
#pragma unroll
        for (int msk = 8; msk >= 1; msk >>= 1) v += __shfl_xor(v, msk, 16);
        lrow[r] = v;
    }
#pragma unroll
    for (int db = 0; db < 4; ++db) {
#pragma unroll
        for (int r = 0; r < 4; ++r) {
            float denom = lrow[r];
            float v = (denom > 0.f) ? oacc[db][r] / denom : 0.f;
            O[((size_t)bz * L + q0 + w * 16 + lg * 4 + r) * 512 + h * 64 + db * 16 + lq] = f2b(v);
        }
    }
}

// ---------- host ----------
extern "C" void kernel_launch(void* const* d_in, const int* in_sizes, int n_in,
                              void* d_out, int out_size, void* d_ws, size_t ws_size,
                              hipStream_t stream) {
    const int M = 4096, D = 512, DFF = 2048, Bz = 4, Lz = 1024, Hz = 8;
    const float* LL = (const float*)d_in[0];
    const float* LH = (const float*)d_in[1];
    const float* raw_tau = (const float*)d_in[2];
    auto F = [&](int i) { return (const float*)d_in[i]; };
    const int BIG = 1 << 28;

    char* p = (char*)d_ws;
    auto alloc = [&](size_t bytes) { void* r = (void*)p; p += (bytes + 255) & ~(size_t)255; return r; };
    const size_t MDf = (size_t)M * D * 4, MDb = (size_t)M * D * 2;
    float* ll_s_f = (float*)alloc(MDf);
    float* lh_s_f = (float*)alloc(MDf);
    u16* ll_s_b = (u16*)alloc(MDb);
    u16* lh_s_b = (u16*)alloc(MDb);
    u16* Qp = (u16*)alloc(2 * MDb);
    u16* Kp = (u16*)alloc(2 * MDb);
    u16* Vt = (u16*)alloc(2 * MDb);
    u16* Cxb = (u16*)alloc(2 * MDb);
    float* ll_o_f = (float*)alloc(MDf);
    u16* ll_o_b = (u16*)alloc(MDb);
    float* lh_o_f = (float*)alloc(MDf);
    u16* lh_o_b = (u16*)alloc(MDb);
    float* cr_o_f = (float*)alloc(MDf);
    float* ln_f_ll = (float*)alloc(MDf);
    float* ln_f_lh = (float*)alloc(MDf);
    u16* ln_b = (u16*)alloc(MDb);
    u16* hb = (u16*)alloc((size_t)M * DFF * 2);
    float* yf_ll = (float*)alloc(MDf);
    float* yf_lh = (float*)alloc(MDf);
    float* kbias = (float*)alloc(4096 * 4);
    float* bqkv_ll = (float*)alloc(1536 * 4);
    float* bqkv_lh = (float*)alloc(1536 * 4);
    float* bkv_cr = (float*)alloc(1024 * 4);
    const size_t WDD = (size_t)262144;
    u16* wqkv_ll = (u16*)alloc(3 * WDD * 2);
    u16* wqkv_lh = (u16*)alloc(3 * WDD * 2);
    u16* wkv_cr = (u16*)alloc(2 * WDD * 2);
    u16* wq_cr = (u16*)alloc(WDD * 2);
    u16* wo_ll = (u16*)alloc(WDD * 2);
    u16* wo_lh = (u16*)alloc(WDD * 2);
    u16* wo_cr = (u16*)alloc(WDD * 2);
    u16* wm[4];
    for (int i = 0; i < 4; ++i) wm[i] = (u16*)alloc((size_t)1048576 * 2);

    const size_t SET = (size_t)4 * 8 * 1024 * 64;

    ConvArgs ca;
    ca.e[0] = {F(3), wqkv_ll, (int)WDD};
    ca.e[1] = {F(5), wqkv_ll + WDD, (int)WDD};
    ca.e[2] = {F(7), wqkv_ll + 2 * WDD, (int)WDD};
    ca.e[3] = {F(11), wqkv_lh, (int)WDD};
    ca.e[4] = {F(13), wqkv_lh + WDD, (int)WDD};
    ca.e[5] = {F(15), wqkv_lh + 2 * WDD, (int)WDD};
    ca.e[6] = {F(19), wq_cr, (int)WDD};
    ca.e[7] = {F(21), wkv_cr, (int)WDD};
    ca.e[8] = {F(23), wkv_cr + WDD, (int)WDD};
    ca.e[9] = {F(9), wo_ll, (int)WDD};
    ca.e[10] = {F(17), wo_lh, (int)WDD};
    ca.e[11] = {F(25), wo_cr, (int)WDD};
    ca.e[12] = {F(27), wm[0], 1048576};
    ca.e[13] = {F(29), wm[1], 1048576};
    ca.e[14] = {F(31), wm[2], 1048576};
    ca.e[15] = {F(33), wm[3], 1048576};
    k_conv<<<dim3(1024, 16), 256, 0, stream>>>(ca);

    CpyArgs cp;
    cp.e[0] = {F(4), bqkv_ll};
    cp.e[1] = {F(6), bqkv_ll + 512};
    cp.e[2] = {F(8), bqkv_ll + 1024};
    cp.e[3] = {F(12), bqkv_lh};
    cp.e[4] = {F(14), bqkv_lh + 512};
    cp.e[5] = {F(16), bqkv_lh + 1024};
    cp.e[6] = {F(22), bkv_cr};
    cp.e[7] = {F(24), bkv_cr + 512};
    k_cpyf<<<dim3(2, 8), 256, 0, stream>>>(cp);

    k_tin<<<dim3(32, 16, 8), dim3(32, 8), 0, stream>>>(LL, LH, ll_s_f, ll_s_b, lh_s_f, lh_s_b);
    k_mask<<<dim3(1024), 256, 0, stream>>>(lh_s_f, raw_tau, kbias);

    auto desc = [&](const u16* A, const u16* W, const float* bias, int N, int K, int blk0) {
        GDesc g = {};
        g.A = A; g.W = W; g.bias = bias; g.N = N; g.K = K; g.blk0 = blk0;
        g.kB = BIG; g.vB = BIG;
        return g;
    };

    // Batch A: qkv_ll + qkv_lh (128x128)
    {
        GArgs ga; ga.nd = 2; ga.total = 768;
        ga.d[0] = desc(ll_s_b, wqkv_ll, bqkv_ll, 1536, 512, 0);
        ga.d[0].pack = 1; ga.d[0].kB = 512; ga.d[0].vB = 1024;
        ga.d[0].Qp = Qp; ga.d[0].Kp = Kp; ga.d[0].Vt = Vt;
        ga.d[1] = desc(lh_s_b, wqkv_lh, bqkv_lh, 1536, 512, 384);
        ga.d[1].pack = 1; ga.d[1].kB = 512; ga.d[1].vB = 1024;
        ga.d[1].Qp = Qp + SET; ga.d[1].Kp = Kp + SET; ga.d[1].Vt = Vt + SET;
        k_bgemm<128, 128><<<dim3(768), 256, 0, stream>>>(ga);
    }
    // merged self-attention: z<4 = ll, z>=4 = lh (biased)
    k_attn<<<dim3(16, 8, 8), 256, 0, stream>>>(Qp, Kp, Vt, Cxb, kbias);
    // Batch B: wo_ll + wo_lh (64x64)
    {
        GArgs ga; ga.nd = 2; ga.total = 1024;
        ga.d[0] = desc(Cxb, wo_ll, F(10), 512, 512, 0);
        ga.d[0].outf = 1; ga.d[0].outb = 1; ga.d[0].Cf = ll_o_f; ga.d[0].Cb = ll_o_b;
        ga.d[1] = desc(Cxb + SET, wo_lh, F(18), 512, 512, 512);
        ga.d[1].outf = 1; ga.d[1].outb = 1; ga.d[1].Cf = lh_o_f; ga.d[1].Cb = lh_o_b;
        k_bgemm<64, 64><<<dim3(1024), 256, 0, stream>>>(ga);
    }
    k_ln<<<dim3(1024), 256, 0, stream>>>(lh_s_f, lh_o_f, nullptr, F(37), F(38), ln_f_lh, ln_b);
    // Batch C: crQ + crKV + mlp_lh_up (128x64)
    {
        GArgs ga; ga.nd = 3; ga.total = 1792;
        ga.d[0] = desc(ll_o_b, wq_cr, F(20), 512, 512, 0);
        ga.d[0].pack = 1; ga.d[0].kB = BIG; ga.d[0].vB = BIG; ga.d[0].Qp = Qp;
        ga.d[1] = desc(lh_o_b, wkv_cr, bkv_cr, 1024, 512, 256);
        ga.d[1].pack = 1; ga.d[1].kB = 0; ga.d[1].vB = 512; ga.d[1].Kp = Kp; ga.d[1].Vt = Vt;
        ga.d[2] = desc(ln_b, wm[2], F(32), 2048, 512, 768);
        ga.d[2].gelu = 1; ga.d[2].outb = 1; ga.d[2].Cb = hb;
        k_bgemm<128, 64><<<dim3(1792), 256, 0, stream>>>(ga);
    }
    // cross attention (z<4, no bias)
    k_attn<<<dim3(16, 8, 4), 256, 0, stream>>>(Qp, Kp, Vt, Cxb, nullptr);
    // Batch D: wo_cr + mlp_lh_down (64x64)
    {
        GArgs ga; ga.nd = 2; ga.total = 1024;
        ga.d[0] = desc(Cxb, wo_cr, F(26), 512, 512, 0);
        ga.d[0].outf = 1; ga.d[0].Cf = cr_o_f;
        ga.d[1] = desc(hb, wm[3], F(34), 512, 2048, 512);
        ga.d[1].outf = 1; ga.d[1].isres = 1; ga.d[1].Cf = yf_lh; ga.d[1].res = ln_f_lh;
        k_bgemm<64, 64><<<dim3(1024), 256, 0, stream>>>(ga);
    }
    k_ln<<<dim3(1024), 256, 0, stream>>>(ll_s_f, ll_o_f, cr_o_f, F(35), F(36), ln_f_ll, ln_b);
    // Batch E: mlp_ll_up (128x128)
    {
        GArgs ga; ga.nd = 1; ga.total = 512;
        ga.d[0] = desc(ln_b, wm[0], F(28), 2048, 512, 0);
        ga.d[0].gelu = 1; ga.d[0].outb = 1; ga.d[0].Cb = hb;
        k_bgemm<128, 128><<<dim3(512), 256, 0, stream>>>(ga);
    }
    // Batch F: mlp_ll_down (64x64)
    {
        GArgs ga; ga.nd = 1; ga.total = 512;
        ga.d[0] = desc(hb, wm[1], F(30), 512, 2048, 0);
        ga.d[0].outf = 1; ga.d[0].isres = 1; ga.d[0].Cf = yf_ll; ga.d[0].res = ln_f_ll;
        k_bgemm<64, 64><<<dim3(512), 256, 0, stream>>>(ga);
    }
    k_tout<<<dim3(32, 16, 8), dim3(32, 8), 0, stream>>>(yf_ll, yf_lh, (float*)d_out);
}

// Round 6
// 277.904 us; speedup vs baseline: 1.2170x; 1.2170x over previous
//
#include <hip/hip_runtime.h>
#include <hip/hip_bf16.h>
#include <stdint.h>

typedef unsigned short u16;
typedef __bf16 bf16_t;
typedef bf16_t bf16x8 __attribute__((ext_vector_type(8)));
typedef float f32x4 __attribute__((ext_vector_type(4)));

#define DEV static __device__ __forceinline__

// ---------- helpers ----------
DEV u16 f2b(float f) {
    __hip_bfloat16 h = __float2bfloat16(f);
    return __builtin_bit_cast(u16, h);
}

DEV bf16x8 ld_frag(const u16* p) {
    uint4 u = *reinterpret_cast<const uint4*>(p);
    return __builtin_bit_cast(bf16x8, u);
}

// exact-GELU via tanh identity (max abs err ~3e-4; margin is 0.07)
DEV float gelu(float v) {
    float y = 0.79788456080286536f * (v + 0.044715f * v * v * v);
    float e = __expf(-2.f * fabsf(y));
    float th = (1.f - e) / (1.f + e);
    th = copysignf(th, y);
    return 0.5f * v * (1.f + th);
}

DEV void gl_lds16(const u16* g, u16* l) {
    __builtin_amdgcn_global_load_lds(
        (const __attribute__((address_space(1))) void*)(uintptr_t)g,
        (__attribute__((address_space(3))) void*)(unsigned int)(uintptr_t)l,
        16, 0, 0);
}

// ---------- weight fp32 -> bf16 conversion ----------
struct ConvEnt { const float* s; u16* d; int n; };
struct ConvArgs { ConvEnt e[16]; };

__global__ __launch_bounds__(256) void k_conv(ConvArgs a) {
    const ConvEnt en = a.e[blockIdx.y];
    for (int i = (blockIdx.x * 256 + threadIdx.x) * 4; i < en.n; i += 256 * 256 * 4) {
        const float4 f = *reinterpret_cast<const float4*>(en.s + i);
        unsigned r0 = (unsigned)f2b(f.x) | ((unsigned)f2b(f.y) << 16);
        unsigned r1 = (unsigned)f2b(f.z) | ((unsigned)f2b(f.w) << 16);
        uint2 rr; rr.x = r0; rr.y = r1;
        *reinterpret_cast<uint2*>(en.d + i) = rr;
    }
}

// ---------- fused-bias concat ----------
struct CpyEnt { const float* s; float* d; };
struct CpyArgs { CpyEnt e[8]; };

__global__ __launch_bounds__(256) void k_cpyf(CpyArgs a) {
    const CpyEnt en = a.e[blockIdx.y];
    int i = blockIdx.x * 256 + threadIdx.x;
    en.d[i] = en.s[i];
}

// ---------- merged transpose in ----------
__global__ __launch_bounds__(256) void k_tin(const float* __restrict__ LL, const float* __restrict__ LH,
                                             float* __restrict__ llf, u16* __restrict__ llb,
                                             float* __restrict__ lhf, u16* __restrict__ lhb) {
    __shared__ float t[32][33];
    int z = blockIdx.z, b = z & 3;
    const float* in = (z < 4) ? LL : LH;
    float* of = (z < 4) ? llf : lhf;
    u16* ob = (z < 4) ? llb : lhb;
    int l0 = blockIdx.x * 32, d0 = blockIdx.y * 32;
    int tx = threadIdx.x, ty = threadIdx.y;
#pragma unroll
    for (int j = 0; j < 4; ++j) {
        int d = d0 + ty + j * 8;
        t[ty + j * 8][tx] = in[((size_t)b * 512 + d) * 1024 + l0 + tx];
    }
    __syncthreads();
#pragma unroll
    for (int j = 0; j < 4; ++j) {
        int l = l0 + ty + j * 8;
        float v = t[tx][ty + j * 8];
        size_t o = ((size_t)b * 1024 + l) * 512 + d0 + tx;
        of[o] = v;
        ob[o] = f2b(v);
    }
}

// ---------- merged transpose out ----------
__global__ __launch_bounds__(256) void k_tout(const float* __restrict__ y0, const float* __restrict__ y1,
                                              float* __restrict__ out) {
    __shared__ float t[32][33];
    int z = blockIdx.z, b = z & 3;
    const float* in = (z < 4) ? y0 : y1;
    float* o = out + ((z < 4) ? 0 : (size_t)4096 * 512);
    int l0 = blockIdx.x * 32, d0 = blockIdx.y * 32;
    int tx = threadIdx.x, ty = threadIdx.y;
#pragma unroll
    for (int j = 0; j < 4; ++j) {
        int l = l0 + ty + j * 8;
        t[ty + j * 8][tx] = in[((size_t)b * 1024 + l) * 512 + d0 + tx];
    }
    __syncthreads();
#pragma unroll
    for (int j = 0; j < 4; ++j) {
        int d = d0 + ty + j * 8;
        o[((size_t)b * 512 + d) * 1024 + l0 + tx] = t[tx][ty + j * 8];
    }
}

// ---------- energy mask ----------
__global__ __launch_bounds__(256) void k_mask(const float* __restrict__ lh_s,
                                              const float* __restrict__ raw_tau,
                                              float* __restrict__ kbias) {
    int row = blockIdx.x * 4 + (threadIdx.x >> 6);
    int lane = threadIdx.x & 63;
    const float* p = lh_s + (size_t)row * 512 + lane * 8;
    float s = 0.f;
#pragma unroll
    for (int j = 0; j < 8; ++j) s += fabsf(p[j]);
#pragma unroll
    for (int m = 32; m >= 1; m >>= 1) s += __shfl_xor(s, m, 64);
    float tau = 1.f / (1.f + expf(-raw_tau[0]));
    if (lane == 0) kbias[row] = (s * (1.f / 512.f) > tau) ? 0.f : -3.0e38f;
}

// ---------- LayerNorm ----------
__global__ __launch_bounds__(256) void k_ln(const float* __restrict__ a, const float* __restrict__ b,
                                            const float* __restrict__ c, const float* __restrict__ w,
                                            const float* __restrict__ bi,
                                            float* __restrict__ of, u16* __restrict__ ob) {
    int row = blockIdx.x * 4 + (threadIdx.x >> 6);
    int lane = threadIdx.x & 63;
    size_t base = (size_t)row * 512 + lane * 8;
    float x[8];
#pragma unroll
    for (int j = 0; j < 8; ++j) {
        float v = a[base + j] + b[base + j];
        if (c) v += c[base + j];
        x[j] = v;
    }
    float s = 0.f, s2 = 0.f;
#pragma unroll
    for (int j = 0; j < 8; ++j) { s += x[j]; s2 += x[j] * x[j]; }
#pragma unroll
    for (int m = 32; m >= 1; m >>= 1) { s += __shfl_xor(s, m, 64); s2 += __shfl_xor(s2, m, 64); }
    float mean = s * (1.f / 512.f);
    float var = s2 * (1.f / 512.f) - mean * mean;
    float rs = rsqrtf(var + 1e-5f);
#pragma unroll
    for (int j = 0; j < 8; ++j) {
        float y = (x[j] - mean) * rs * w[lane * 8 + j] + bi[lane * 8 + j];
        of[base + j] = y;
        ob[base + j] = f2b(y);
    }
}

// ---------- bf16 MFMA GEMM, dbuf + T2 swizzle + LDS-transposed V pack ----------
// C[M,N] = A[M,K] @ W[N,K]^T + bias; flat grid (n-fastest), XCD-bijective swizzle.
template <int BM, int BN, int GELU_ACT, int OUTF, int OUTB, int RES, int PACK>
__global__ __launch_bounds__(256) void k_gemm(const u16* __restrict__ A, const u16* __restrict__ W,
                                              const float* __restrict__ bias,
                                              const float* __restrict__ res,
                                              float* __restrict__ Cf, u16* __restrict__ Cb,
                                              u16* __restrict__ Qp, u16* __restrict__ Kp,
                                              u16* __restrict__ Vt, int kB, int vB,
                                              int M, int N, int K, int nwg) {
    constexpr int BK = 64;
    __shared__ alignas(16) u16 Al[2][BM * BK];
    __shared__ alignas(16) u16 Wl[2][BN * BK];
    // bijective XCD-chunk swizzle (m204)
    int bid;
    {
        const int orig = blockIdx.x;
        const int xcd = orig & 7, lin = orig >> 3;
        const int q = nwg >> 3, r = nwg & 7;
        bid = (xcd < r ? xcd * (q + 1) : r * (q + 1) + (xcd - r) * q) + lin;
    }
    const int nny = N / BN;
    const int m0 = (bid / nny) * BM, n0 = (bid % nny) * BN;

    const int t = threadIdx.x, w = t >> 6, l = t & 63;
    constexpr int FM = BM / 32, FN = BN / 32;
    const int wr = w >> 1, wc = w & 1;
    const int lq = l & 15, lg = l >> 4;
    f32x4 acc[FM][FN] = {};

    const int srow = l >> 3, schunk = l & 7;
    // source column pre-swizzled so LDS row holds chunk^(row&7) at linear slot
    auto stage = [&](int kcol, int buf) {
#pragma unroll
        for (int i = 0; i < BM / 32; ++i) {
            const int row = i * 32 + w * 8 + srow;
            gl_lds16(A + (size_t)(m0 + row) * K + kcol + ((schunk ^ (row & 7)) * 8),
                     &Al[buf][(i * 32 + w * 8) * BK]);
        }
#pragma unroll
        for (int i = 0; i < BN / 32; ++i) {
            const int row = i * 32 + w * 8 + srow;
            gl_lds16(W + (size_t)(n0 + row) * K + kcol + ((schunk ^ (row & 7)) * 8),
                     &Wl[buf][(i * 32 + w * 8) * BK]);
        }
    };

    stage(0, 0);
    const int KT = K / BK;
    for (int kt = 0; kt < KT; ++kt) {
        const int cur = kt & 1;
        __syncthreads();  // drains stage(kt) issued one compute-phase ago
        if (kt + 1 < KT) stage((kt + 1) * BK, cur ^ 1);
#pragma unroll
        for (int s = 0; s < 2; ++s) {
            bf16x8 af[FM], bw[FN];
#pragma unroll
            for (int i = 0; i < FM; ++i) {
                const int row = wr * (BM / 2) + i * 16 + lq;
                af[i] = ld_frag(&Al[cur][row * BK + (((s * 4 + lg) ^ (row & 7)) * 8)]);
            }
#pragma unroll
            for (int j = 0; j < FN; ++j) {
                const int row = wc * (BN / 2) + j * 16 + lq;
                bw[j] = ld_frag(&Wl[cur][row * BK + (((s * 4 + lg) ^ (row & 7)) * 8)]);
            }
#pragma unroll
            for (int i = 0; i < FM; ++i)
#pragma unroll
                for (int j = 0; j < FN; ++j)
                    acc[i][j] = __builtin_amdgcn_mfma_f32_16x16x32_bf16(af[i], bw[j], acc[i][j], 0, 0, 0);
        }
    }

    if (PACK && n0 >= vB) {
        // V pack: LDS transpose (swizzled) -> coalesced 16B row stores into Vt[bh][d][1024]
        u16* T = (u16*)Al;  // 2*BM*BK u16 >= BN*BM
        constexpr int CH = BM / 8, CMASK = CH - 1, SH = (CH == 16) ? 4 : 3;
        __syncthreads();  // K-loop LDS reads finished in all waves
#pragma unroll
        for (int i = 0; i < FM; ++i) {
#pragma unroll
            for (int j = 0; j < FN; ++j) {
                const int ni = wc * (BN / 2) + j * 16 + lq;
                const float bn = bias[n0 + ni];
#pragma unroll
                for (int r2 = 0; r2 < 4; ++r2) {
                    const int mi = wr * (BM / 2) + i * 16 + lg * 4 + r2;
                    T[ni * BM + (((mi >> 3) ^ (ni & CMASK)) * 8) + (mi & 7)] = f2b(acc[i][j][r2] + bn);
                }
            }
        }
        __syncthreads();
        const int bb = m0 >> 10, mloc = m0 & 1023;
        const int mc = t & CMASK, nib = t >> SH;
        constexpr int RPP = 256 / CH;
#pragma unroll
        for (int p2 = 0; p2 < BN / RPP; ++p2) {
            const int ni = nib + p2 * RPP;
            uint4 u = *reinterpret_cast<const uint4*>(&T[ni * BM + ((mc ^ (ni & CMASK)) * 8)]);
            const int d = n0 - vB + ni;
            *reinterpret_cast<uint4*>(
                &Vt[((size_t)(bb * 8 + (d >> 6)) * 64 + (d & 63)) * 1024 + mloc + mc * 8]) = u;
        }
        return;
    }

#pragma unroll
    for (int i = 0; i < FM; ++i) {
#pragma unroll
        for (int j = 0; j < FN; ++j) {
            const int n = n0 + wc * (BN / 2) + j * 16 + lq;
            const float bn = bias[n];
#pragma unroll
            for (int r2 = 0; r2 < 4; ++r2) {
                const int m = m0 + wr * (BM / 2) + i * 16 + lg * 4 + r2;
                float v = acc[i][j][r2] + bn;
                if (GELU_ACT) v = gelu(v);
                if (PACK) {
                    const int bb = m >> 10, ll_ = m & 1023;
                    if (n >= kB) {
                        const int d = n - kB;
                        Kp[((size_t)(bb * 8 + (d >> 6)) * 1024 + ll_) * 64 + (d & 63)] = f2b(v);
                    } else {
                        Qp[((size_t)(bb * 8 + (n >> 6)) * 1024 + ll_) * 64 + (n & 63)] = f2b(v * 0.125f);
                    }
                } else {
                    size_t o = (size_t)m * N + n;
                    if (RES) v += res[o];
                    if (OUTF) Cf[o] = v;
                    if (OUTB) Cb[o] = f2b(v);
                }
            }
        }
    }
}

// ---------- flash attention: 2-phase dbuf, no-max softmax, deferred denom ----------
__global__ __launch_bounds__(256) void k_attn(const u16* __restrict__ Qp, const u16* __restrict__ Kp,
                                              const u16* __restrict__ Vtp, u16* __restrict__ O,
                                              const float* __restrict__ kbias) {
    constexpr int L = 1024;
    __shared__ alignas(16) u16 Kl[2][64 * 64];
    __shared__ alignas(16) u16 Vl[2][64 * 64];
    __shared__ alignas(16) u16 Pl[64 * 72];
    const int t = threadIdx.x, w = t >> 6, l = t & 63;
    const int q0 = blockIdx.x * 64;
    const int h = blockIdx.y, bz = blockIdx.z, bh = bz * 8 + h;
    const int lq = l & 15, lg = l >> 4;
    const float* kb = (kbias != nullptr && bz >= 4) ? (kbias + (size_t)(bz - 4) * L) : nullptr;

    bf16x8 qa0, qa1;
    {
        const u16* qp = Qp + ((size_t)bh * L + q0 + w * 16 + lq) * 64 + lg * 8;
        qa0 = ld_frag(qp);
        qa1 = ld_frag(qp + 32);
    }

    const int r0 = w * 16 + (l >> 3), r1 = r0 + 8, c = l & 7;
    const u16* Ksrc0 = Kp + (size_t)bh * L * 64 + (size_t)r0 * 64 + ((c ^ (r0 & 7)) * 8);
    const u16* Ksrc1 = Kp + (size_t)bh * L * 64 + (size_t)r1 * 64 + ((c ^ (r1 & 7)) * 8);
    const u16* Vsrc0 = Vtp + (size_t)bh * 64 * L + (size_t)r0 * L + ((c ^ (r0 & 7)) * 8);
    const u16* Vsrc1 = Vtp + (size_t)bh * 64 * L + (size_t)r1 * L + ((c ^ (r1 & 7)) * 8);

    auto stage = [&](int k0, int buf) {
        gl_lds16(Ksrc0 + (size_t)k0 * 64, &Kl[buf][(w * 16) * 64]);
        gl_lds16(Ksrc1 + (size_t)k0 * 64, &Kl[buf][(w * 16 + 8) * 64]);
        gl_lds16(Vsrc0 + k0, &Vl[buf][(w * 16) * 64]);
        gl_lds16(Vsrc1 + k0, &Vl[buf][(w * 16 + 8) * 64]);
    };

    int addrA[4][2];
#pragma unroll
    for (int f = 0; f < 4; ++f) {
        int row = f * 16 + lq;
#pragma unroll
        for (int s = 0; s < 2; ++s) addrA[f][s] = row * 64 + (((s * 4 + lg) ^ (row & 7)) * 8);
    }
    const int paddr0 = (w * 16 + lq) * 72 + lg * 8;

    f32x4 oacc[4] = {};
    float lrow[4] = {0.f, 0.f, 0.f, 0.f};

    stage(0, 0);
    for (int kt = 0; kt < 16; ++kt) {
        const int cur = kt & 1;
        __syncthreads();
        if (kt + 1 < 16) stage((kt + 1) * 64, cur ^ 1);

        f32x4 sc4[4];
#pragma unroll
        for (int f = 0; f < 4; ++f) {
            f32x4 a = {};
            a = __builtin_amdgcn_mfma_f32_16x16x32_bf16(qa0, ld_frag(&Kl[cur][addrA[f][0]]), a, 0, 0, 0);
            a = __builtin_amdgcn_mfma_f32_16x16x32_bf16(qa1, ld_frag(&Kl[cur][addrA[f][1]]), a, 0, 0, 0);
            sc4[f] = a;
        }
#pragma unroll
        for (int f = 0; f < 4; ++f) {
            float bv = kb ? kb[kt * 64 + f * 16 + lq] : 0.f;
#pragma unroll
            for (int r = 0; r < 4; ++r) {
                float pv = __expf(sc4[f][r] + bv);
                lrow[r] += pv;
                Pl[(w * 16 + lg * 4 + r) * 72 + f * 16 + lq] = f2b(pv);
            }
        }
        bf16x8 pa0 = ld_frag(&Pl[paddr0]);
        bf16x8 pa1 = ld_frag(&Pl[paddr0 + 32]);
#pragma unroll
        for (int db = 0; db < 4; ++db) {
            oacc[db] = __builtin_amdgcn_mfma_f32_16x16x32_bf16(pa0, ld_frag(&Vl[cur][addrA[db][0]]), oacc[db], 0, 0, 0);
            oacc[db] = __builtin_amdgcn_mfma_f32_16x16x32_bf16(pa1, ld_frag(&Vl[cur][addrA[db][1]]), oacc[db], 0, 0, 0);
        }
    }
#pragma unroll
    for (int r = 0; r < 4; ++r) {
        float v = lrow[r];
#pragma unroll
        for (int msk = 8; msk >= 1; msk >>= 1) v += __shfl_xor(v, msk, 16);
        lrow[r] = v;
    }
#pragma unroll
    for (int db = 0; db < 4; ++db) {
#pragma unroll
        for (int r = 0; r < 4; ++r) {
            float denom = lrow[r];
            float v = (denom > 0.f) ? oacc[db][r] / denom : 0.f;
            O[((size_t)bz * L + q0 + w * 16 + lg * 4 + r) * 512 + h * 64 + db * 16 + lq] = f2b(v);
        }
    }
}

// ---------- host ----------
extern "C" void kernel_launch(void* const* d_in, const int* in_sizes, int n_in,
                              void* d_out, int out_size, void* d_ws, size_t ws_size,
                              hipStream_t stream) {
    const int M = 4096, D = 512, DFF = 2048, Hz = 8;
    const float* LL = (const float*)d_in[0];
    const float* LH = (const float*)d_in[1];
    const float* raw_tau = (const float*)d_in[2];
    auto F = [&](int i) { return (const float*)d_in[i]; };
    const int BIG = 1 << 28;

    char* p = (char*)d_ws;
    auto alloc = [&](size_t bytes) { void* r = (void*)p; p += (bytes + 255) & ~(size_t)255; return r; };
    const size_t MDf = (size_t)M * D * 4, MDb = (size_t)M * D * 2;
    float* ll_s_f = (float*)alloc(MDf);
    float* lh_s_f = (float*)alloc(MDf);
    u16* ll_s_b = (u16*)alloc(MDb);
    u16* lh_s_b = (u16*)alloc(MDb);
    u16* Qp = (u16*)alloc(2 * MDb);
    u16* Kp = (u16*)alloc(2 * MDb);
    u16* Vt = (u16*)alloc(2 * MDb);
    u16* Cxb = (u16*)alloc(2 * MDb);
    float* ll_o_f = (float*)alloc(MDf);
    u16* ll_o_b = (u16*)alloc(MDb);
    float* lh_o_f = (float*)alloc(MDf);
    u16* lh_o_b = (u16*)alloc(MDb);
    float* cr_o_f = (float*)alloc(MDf);
    float* ln_f_ll = (float*)alloc(MDf);
    float* ln_f_lh = (float*)alloc(MDf);
    u16* ln_b = (u16*)alloc(MDb);
    u16* hb = (u16*)alloc((size_t)M * DFF * 2);
    float* yf_ll = (float*)alloc(MDf);
    float* yf_lh = (float*)alloc(MDf);
    float* kbias = (float*)alloc(4096 * 4);
    float* bqkv_ll = (float*)alloc(1536 * 4);
    float* bqkv_lh = (float*)alloc(1536 * 4);
    float* bkv_cr = (float*)alloc(1024 * 4);
    const size_t WDD = (size_t)262144;
    u16* wqkv_ll = (u16*)alloc(3 * WDD * 2);
    u16* wqkv_lh = (u16*)alloc(3 * WDD * 2);
    u16* wkv_cr = (u16*)alloc(2 * WDD * 2);
    u16* wq_cr = (u16*)alloc(WDD * 2);
    u16* wo_ll = (u16*)alloc(WDD * 2);
    u16* wo_lh = (u16*)alloc(WDD * 2);
    u16* wo_cr = (u16*)alloc(WDD * 2);
    u16* wm[4];
    for (int i = 0; i < 4; ++i) wm[i] = (u16*)alloc((size_t)1048576 * 2);

    const size_t SET = (size_t)4 * 8 * 1024 * 64;

    ConvArgs ca;
    ca.e[0] = {F(3), wqkv_ll, (int)WDD};
    ca.e[1] = {F(5), wqkv_ll + WDD, (int)WDD};
    ca.e[2] = {F(7), wqkv_ll + 2 * WDD, (int)WDD};
    ca.e[3] = {F(11), wqkv_lh, (int)WDD};
    ca.e[4] = {F(13), wqkv_lh + WDD, (int)WDD};
    ca.e[5] = {F(15), wqkv_lh + 2 * WDD, (int)WDD};
    ca.e[6] = {F(19), wq_cr, (int)WDD};
    ca.e[7] = {F(21), wkv_cr, (int)WDD};
    ca.e[8] = {F(23), wkv_cr + WDD, (int)WDD};
    ca.e[9] = {F(9), wo_ll, (int)WDD};
    ca.e[10] = {F(17), wo_lh, (int)WDD};
    ca.e[11] = {F(25), wo_cr, (int)WDD};
    ca.e[12] = {F(27), wm[0], 1048576};
    ca.e[13] = {F(29), wm[1], 1048576};
    ca.e[14] = {F(31), wm[2], 1048576};
    ca.e[15] = {F(33), wm[3], 1048576};
    k_conv<<<dim3(256, 16), 256, 0, stream>>>(ca);

    CpyArgs cp;
    cp.e[0] = {F(4), bqkv_ll};
    cp.e[1] = {F(6), bqkv_ll + 512};
    cp.e[2] = {F(8), bqkv_ll + 1024};
    cp.e[3] = {F(12), bqkv_lh};
    cp.e[4] = {F(14), bqkv_lh + 512};
    cp.e[5] = {F(16), bqkv_lh + 1024};
    cp.e[6] = {F(22), bkv_cr};
    cp.e[7] = {F(24), bkv_cr + 512};
    k_cpyf<<<dim3(2, 8), 256, 0, stream>>>(cp);

    k_tin<<<dim3(32, 16, 8), dim3(32, 8), 0, stream>>>(LL, LH, ll_s_f, ll_s_b, lh_s_f, lh_s_b);
    k_mask<<<dim3(1024), 256, 0, stream>>>(lh_s_f, raw_tau, kbias);

    // qkv_ll / qkv_lh (128x128, grid 384 each)
    k_gemm<128, 128, 0, 0, 0, 0, 1><<<dim3(384), 256, 0, stream>>>(
        ll_s_b, wqkv_ll, bqkv_ll, nullptr, nullptr, nullptr, Qp, Kp, Vt, 512, 1024, M, 1536, 512, 384);
    k_gemm<128, 128, 0, 0, 0, 0, 1><<<dim3(384), 256, 0, stream>>>(
        lh_s_b, wqkv_lh, bqkv_lh, nullptr, nullptr, nullptr, Qp + SET, Kp + SET, Vt + SET, 512, 1024, M, 1536, 512, 384);
    // merged self-attention
    k_attn<<<dim3(16, 8, 8), 256, 0, stream>>>(Qp, Kp, Vt, Cxb, kbias);
    // wo_ll / wo_lh (64x64, grid 512)
    k_gemm<64, 64, 0, 1, 1, 0, 0><<<dim3(512), 256, 0, stream>>>(
        Cxb, wo_ll, F(10), nullptr, ll_o_f, ll_o_b, nullptr, nullptr, nullptr, 0, BIG, M, 512, 512, 512);
    k_gemm<64, 64, 0, 1, 1, 0, 0><<<dim3(512), 256, 0, stream>>>(
        Cxb + SET, wo_lh, F(18), nullptr, lh_o_f, lh_o_b, nullptr, nullptr, nullptr, 0, BIG, M, 512, 512, 512);
    // lh LN + mlp_lh_up
    k_ln<<<dim3(1024), 256, 0, stream>>>(lh_s_f, lh_o_f, nullptr, F(37), F(38), ln_f_lh, ln_b);
    k_gemm<128, 128, 1, 0, 1, 0, 0><<<dim3(512), 256, 0, stream>>>(
        ln_b, wm[2], F(32), nullptr, nullptr, hb, nullptr, nullptr, nullptr, 0, BIG, M, 2048, 512, 512);
    // cross Q / KV
    k_gemm<64, 64, 0, 0, 0, 0, 1><<<dim3(512), 256, 0, stream>>>(
        ll_o_b, wq_cr, F(20), nullptr, nullptr, nullptr, Qp, Kp, Vt, BIG, BIG, M, 512, 512, 512);
    k_gemm<64, 64, 0, 0, 0, 0, 1><<<dim3(1024), 256, 0, stream>>>(
        lh_o_b, wkv_cr, bkv_cr, nullptr, nullptr, nullptr, Qp, Kp, Vt, 0, 512, M, 1024, 512, 1024);
    // cross attention
    k_attn<<<dim3(16, 8, 4), 256, 0, stream>>>(Qp, Kp, Vt, Cxb, nullptr);
    // wo_cr + mlp_lh_down
    k_gemm<64, 64, 0, 1, 0, 0, 0><<<dim3(512), 256, 0, stream>>>(
        Cxb, wo_cr, F(26), nullptr, cr_o_f, nullptr, nullptr, nullptr, nullptr, 0, BIG, M, 512, 512, 512);
    k_gemm<64, 64, 0, 1, 0, 1, 0><<<dim3(512), 256, 0, stream>>>(
        hb, wm[3], F(34), ln_f_lh, yf_lh, nullptr, nullptr, nullptr, nullptr, 0, BIG, M, 512, 2048, 512);
    // ll LN + MLP
    k_ln<<<dim3(1024), 256, 0, stream>>>(ll_s_f, ll_o_f, cr_o_f, F(35), F(36), ln_f_ll, ln_b);
    k_gemm<128, 128, 1, 0, 1, 0, 0><<<dim3(512), 256, 0, stream>>>(
        ln_b, wm[0], F(28), nullptr, nullptr, hb, nullptr, nullptr, nullptr, 0, BIG, M, 2048, 512, 512);
    k_gemm<64, 64, 0, 1, 0, 1, 0><<<dim3(512), 256, 0, stream>>>(
        hb, wm[1], F(30), ln_f_ll, yf_ll, nullptr, nullptr, nullptr, nullptr, 0, BIG, M, 512, 2048, 512);
    k_tout<<<dim3(32, 16, 8), dim3(32, 8), 0, stream>>>(yf_ll, yf_lh, (float*)d_out);
}

// Round 7
// 273.893 us; speedup vs baseline: 1.2348x; 1.0146x over previous
//
#include <hip/hip_runtime.h>
#include <hip/hip_bf16.h>
#include <stdint.h>

typedef unsigned short u16;
typedef __bf16 bf16_t;
typedef bf16_t bf16x8 __attribute__((ext_vector_type(8)));
typedef float f32x4 __attribute__((ext_vector_type(4)));

#define DEV static __device__ __forceinline__

// ---------- helpers ----------
DEV u16 f2b(float f) {
    __hip_bfloat16 h = __float2bfloat16(f);
    return __builtin_bit_cast(u16, h);
}

DEV bf16x8 ld_frag(const u16* p) {
    uint4 u = *reinterpret_cast<const uint4*>(p);
    return __builtin_bit_cast(bf16x8, u);
}

// exact-GELU via tanh identity (max abs err ~3e-4; margin is 0.07)
DEV float gelu(float v) {
    float y = 0.79788456080286536f * (v + 0.044715f * v * v * v);
    float e = __expf(-2.f * fabsf(y));
    float th = (1.f - e) / (1.f + e);
    th = copysignf(th, y);
    return 0.5f * v * (1.f + th);
}

DEV void gl_lds16(const u16* g, u16* l) {
    __builtin_amdgcn_global_load_lds(
        (const __attribute__((address_space(1))) void*)(uintptr_t)g,
        (__attribute__((address_space(3))) void*)(unsigned int)(uintptr_t)l,
        16, 0, 0);
}

// ---------- weight fp32 -> bf16 conversion ----------
struct ConvEnt { const float* s; u16* d; int n; };
struct ConvArgs { ConvEnt e[16]; };

__global__ __launch_bounds__(256) void k_conv(ConvArgs a) {
    const ConvEnt en = a.e[blockIdx.y];
    for (int i = (blockIdx.x * 256 + threadIdx.x) * 4; i < en.n; i += 256 * 256 * 4) {
        const float4 f = *reinterpret_cast<const float4*>(en.s + i);
        unsigned r0 = (unsigned)f2b(f.x) | ((unsigned)f2b(f.y) << 16);
        unsigned r1 = (unsigned)f2b(f.z) | ((unsigned)f2b(f.w) << 16);
        uint2 rr; rr.x = r0; rr.y = r1;
        *reinterpret_cast<uint2*>(en.d + i) = rr;
    }
}

// ---------- fused-bias concat ----------
struct CpyEnt { const float* s; float* d; };
struct CpyArgs { CpyEnt e[8]; };

__global__ __launch_bounds__(256) void k_cpyf(CpyArgs a) {
    const CpyEnt en = a.e[blockIdx.y];
    int i = blockIdx.x * 256 + threadIdx.x;
    en.d[i] = en.s[i];
}

// ---------- merged transpose in ----------
__global__ __launch_bounds__(256) void k_tin(const float* __restrict__ LL, const float* __restrict__ LH,
                                             float* __restrict__ llf, u16* __restrict__ llb,
                                             float* __restrict__ lhf, u16* __restrict__ lhb) {
    __shared__ float t[32][33];
    int z = blockIdx.z, b = z & 3;
    const float* in = (z < 4) ? LL : LH;
    float* of = (z < 4) ? llf : lhf;
    u16* ob = (z < 4) ? llb : lhb;
    int l0 = blockIdx.x * 32, d0 = blockIdx.y * 32;
    int tx = threadIdx.x, ty = threadIdx.y;
#pragma unroll
    for (int j = 0; j < 4; ++j) {
        int d = d0 + ty + j * 8;
        t[ty + j * 8][tx] = in[((size_t)b * 512 + d) * 1024 + l0 + tx];
    }
    __syncthreads();
#pragma unroll
    for (int j = 0; j < 4; ++j) {
        int l = l0 + ty + j * 8;
        float v = t[tx][ty + j * 8];
        size_t o = ((size_t)b * 1024 + l) * 512 + d0 + tx;
        of[o] = v;
        ob[o] = f2b(v);
    }
}

// ---------- merged transpose out ----------
__global__ __launch_bounds__(256) void k_tout(const float* __restrict__ y0, const float* __restrict__ y1,
                                              float* __restrict__ out) {
    __shared__ float t[32][33];
    int z = blockIdx.z, b = z & 3;
    const float* in = (z < 4) ? y0 : y1;
    float* o = out + ((z < 4) ? 0 : (size_t)4096 * 512);
    int l0 = blockIdx.x * 32, d0 = blockIdx.y * 32;
    int tx = threadIdx.x, ty = threadIdx.y;
#pragma unroll
    for (int j = 0; j < 4; ++j) {
        int l = l0 + ty + j * 8;
        t[ty + j * 8][tx] = in[((size_t)b * 1024 + l) * 512 + d0 + tx];
    }
    __syncthreads();
#pragma unroll
    for (int j = 0; j < 4; ++j) {
        int d = d0 + ty + j * 8;
        o[((size_t)b * 512 + d) * 1024 + l0 + tx] = t[tx][ty + j * 8];
    }
}

// ---------- energy mask ----------
__global__ __launch_bounds__(256) void k_mask(const float* __restrict__ lh_s,
                                              const float* __restrict__ raw_tau,
                                              float* __restrict__ kbias) {
    int row = blockIdx.x * 4 + (threadIdx.x >> 6);
    int lane = threadIdx.x & 63;
    const float* p = lh_s + (size_t)row * 512 + lane * 8;
    float s = 0.f;
#pragma unroll
    for (int j = 0; j < 8; ++j) s += fabsf(p[j]);
#pragma unroll
    for (int m = 32; m >= 1; m >>= 1) s += __shfl_xor(s, m, 64);
    float tau = 1.f / (1.f + expf(-raw_tau[0]));
    if (lane == 0) kbias[row] = (s * (1.f / 512.f) > tau) ? 0.f : -3.0e38f;
}

// ---------- LayerNorm ----------
__global__ __launch_bounds__(256) void k_ln(const float* __restrict__ a, const float* __restrict__ b,
                                            const float* __restrict__ c, const float* __restrict__ w,
                                            const float* __restrict__ bi,
                                            float* __restrict__ of, u16* __restrict__ ob) {
    int row = blockIdx.x * 4 + (threadIdx.x >> 6);
    int lane = threadIdx.x & 63;
    size_t base = (size_t)row * 512 + lane * 8;
    float x[8];
#pragma unroll
    for (int j = 0; j < 8; ++j) {
        float v = a[base + j] + b[base + j];
        if (c) v += c[base + j];
        x[j] = v;
    }
    float s = 0.f, s2 = 0.f;
#pragma unroll
    for (int j = 0; j < 8; ++j) { s += x[j]; s2 += x[j] * x[j]; }
#pragma unroll
    for (int m = 32; m >= 1; m >>= 1) { s += __shfl_xor(s, m, 64); s2 += __shfl_xor(s2, m, 64); }
    float mean = s * (1.f / 512.f);
    float var = s2 * (1.f / 512.f) - mean * mean;
    float rs = rsqrtf(var + 1e-5f);
#pragma unroll
    for (int j = 0; j < 8; ++j) {
        float y = (x[j] - mean) * rs * w[lane * 8 + j] + bi[lane * 8 + j];
        of[base + j] = y;
        ob[base + j] = f2b(y);
    }
}

// ---------- paired bf16 MFMA GEMM (blockIdx.y selects descriptor) ----------
// C[M,N] = A[M,K] @ W[N,K]^T + bias; dbuf + T2 swizzle; XCD-bijective swizzle.
struct GP {
    const u16* A; const u16* W; const float* bias; const float* res;
    float* Cf; u16* Cb; u16* Qp; u16* Kp; u16* Vt;
    int N, K, kB, vB, nwg;
};

template <int BM, int BN, int GELU_ACT, int PACK>
__global__ __launch_bounds__(256) void k_gemm(GP p0, GP p1, int M) {
    constexpr int BK = 64;
    __shared__ alignas(16) u16 Al[2][BM * BK];
    __shared__ alignas(16) u16 Wl[2][BN * BK];
    GP g = (blockIdx.y == 0) ? p0 : p1;
    const int orig = blockIdx.x;
    if (orig >= g.nwg) return;
    int bid;
    {
        const int xcd = orig & 7, lin = orig >> 3;
        const int q = g.nwg >> 3, r = g.nwg & 7;
        bid = (xcd < r ? xcd * (q + 1) : r * (q + 1) + (xcd - r) * q) + lin;
    }
    const int K = g.K, N = g.N;
    const int nny = N / BN;
    const int m0 = (bid / nny) * BM, n0 = (bid % nny) * BN;

    const int t = threadIdx.x, w = t >> 6, l = t & 63;
    constexpr int FM = BM / 32, FN = BN / 32;
    const int wr = w >> 1, wc = w & 1;
    const int lq = l & 15, lg = l >> 4;
    f32x4 acc[FM][FN] = {};

    const int srow = l >> 3, schunk = l & 7;
    auto stage = [&](int kcol, int buf) {
#pragma unroll
        for (int i = 0; i < BM / 32; ++i) {
            const int row = i * 32 + w * 8 + srow;
            gl_lds16(g.A + (size_t)(m0 + row) * K + kcol + ((schunk ^ (row & 7)) * 8),
                     &Al[buf][(i * 32 + w * 8) * BK]);
        }
#pragma unroll
        for (int i = 0; i < BN / 32; ++i) {
            const int row = i * 32 + w * 8 + srow;
            gl_lds16(g.W + (size_t)(n0 + row) * K + kcol + ((schunk ^ (row & 7)) * 8),
                     &Wl[buf][(i * 32 + w * 8) * BK]);
        }
    };

    stage(0, 0);
    const int KT = K / BK;
    for (int kt = 0; kt < KT; ++kt) {
        const int cur = kt & 1;
        __syncthreads();  // drains stage(kt) issued one compute-phase ago
        if (kt + 1 < KT) stage((kt + 1) * BK, cur ^ 1);
#pragma unroll
        for (int s = 0; s < 2; ++s) {
            bf16x8 af[FM], bw[FN];
#pragma unroll
            for (int i = 0; i < FM; ++i) {
                const int row = wr * (BM / 2) + i * 16 + lq;
                af[i] = ld_frag(&Al[cur][row * BK + (((s * 4 + lg) ^ (row & 7)) * 8)]);
            }
#pragma unroll
            for (int j = 0; j < FN; ++j) {
                const int row = wc * (BN / 2) + j * 16 + lq;
                bw[j] = ld_frag(&Wl[cur][row * BK + (((s * 4 + lg) ^ (row & 7)) * 8)]);
            }
#pragma unroll
            for (int i = 0; i < FM; ++i)
#pragma unroll
                for (int j = 0; j < FN; ++j)
                    acc[i][j] = __builtin_amdgcn_mfma_f32_16x16x32_bf16(af[i], bw[j], acc[i][j], 0, 0, 0);
        }
    }

    if (PACK && n0 >= g.vB) {
        // V pack: LDS transpose (swizzled) -> coalesced 16B row stores into Vt[bh][d][1024]
        u16* T = (u16*)Al;
        constexpr int CH = BM / 8, CMASK = CH - 1, SH = (CH == 16) ? 4 : 3;
        __syncthreads();
#pragma unroll
        for (int i = 0; i < FM; ++i) {
#pragma unroll
            for (int j = 0; j < FN; ++j) {
                const int ni = wc * (BN / 2) + j * 16 + lq;
                const float bn = g.bias[n0 + ni];
#pragma unroll
                for (int r2 = 0; r2 < 4; ++r2) {
                    const int mi = wr * (BM / 2) + i * 16 + lg * 4 + r2;
                    T[ni * BM + (((mi >> 3) ^ (ni & CMASK)) * 8) + (mi & 7)] = f2b(acc[i][j][r2] + bn);
                }
            }
        }
        __syncthreads();
        const int bb = m0 >> 10, mloc = m0 & 1023;
        const int mc = t & CMASK, nib = t >> SH;
        constexpr int RPP = 256 / CH;
#pragma unroll
        for (int p2 = 0; p2 < BN / RPP; ++p2) {
            const int ni = nib + p2 * RPP;
            uint4 u = *reinterpret_cast<const uint4*>(&T[ni * BM + ((mc ^ (ni & CMASK)) * 8)]);
            const int d = n0 - g.vB + ni;
            *reinterpret_cast<uint4*>(
                &g.Vt[((size_t)(bb * 8 + (d >> 6)) * 64 + (d & 63)) * 1024 + mloc + mc * 8]) = u;
        }
        return;
    }

#pragma unroll
    for (int i = 0; i < FM; ++i) {
#pragma unroll
        for (int j = 0; j < FN; ++j) {
            const int n = n0 + wc * (BN / 2) + j * 16 + lq;
            const float bn = g.bias[n];
#pragma unroll
            for (int r2 = 0; r2 < 4; ++r2) {
                const int m = m0 + wr * (BM / 2) + i * 16 + lg * 4 + r2;
                float v = acc[i][j][r2] + bn;
                if (GELU_ACT) v = gelu(v);
                if (PACK) {
                    const int bb = m >> 10, ll_ = m & 1023;
                    if (n >= g.kB) {
                        const int d = n - g.kB;
                        g.Kp[((size_t)(bb * 8 + (d >> 6)) * 1024 + ll_) * 64 + (d & 63)] = f2b(v);
                    } else {
                        g.Qp[((size_t)(bb * 8 + (n >> 6)) * 1024 + ll_) * 64 + (n & 63)] = f2b(v * 0.125f);
                    }
                } else {
                    size_t o = (size_t)m * N + n;
                    if (g.res) v += g.res[o];
                    if (g.Cf) g.Cf[o] = v;
                    if (g.Cb) g.Cb[o] = f2b(v);
                }
            }
        }
    }
}

// ---------- flash attention: 40KB LDS (4 blocks/CU), XCD-chunked 1D grid ----------
__global__ __launch_bounds__(256) void k_attn(const u16* __restrict__ Qp, const u16* __restrict__ Kp,
                                              const u16* __restrict__ Vtp, u16* __restrict__ O,
                                              const float* __restrict__ kbias, int nwg) {
    constexpr int L = 1024;
    __shared__ alignas(16) u16 Kl[2][64 * 64];
    __shared__ alignas(16) u16 Vl[2][64 * 64];
    __shared__ alignas(16) u16 Pl[64 * 64];  // XOR-swizzled, unpadded -> total 40960B
    const int t = threadIdx.x, w = t >> 6, l = t & 63;
    int bid;
    {
        const int orig = blockIdx.x;
        bid = (orig & 7) * (nwg >> 3) + (orig >> 3);  // XCD chunk (nwg % 8 == 0)
    }
    const int bh = bid >> 4, q0 = (bid & 15) * 64;
    const int bz = bh >> 3, h = bh & 7;
    const int lq = l & 15, lg = l >> 4;
    const float* kb = (kbias != nullptr && bz >= 4) ? (kbias + (size_t)(bz - 4) * L) : nullptr;

    bf16x8 qa0, qa1;
    {
        const u16* qp = Qp + ((size_t)bh * L + q0 + w * 16 + lq) * 64 + lg * 8;
        qa0 = ld_frag(qp);
        qa1 = ld_frag(qp + 32);
    }

    const int r0 = w * 16 + (l >> 3), r1 = r0 + 8, c = l & 7;
    const u16* Ksrc0 = Kp + (size_t)bh * L * 64 + (size_t)r0 * 64 + ((c ^ (r0 & 7)) * 8);
    const u16* Ksrc1 = Kp + (size_t)bh * L * 64 + (size_t)r1 * 64 + ((c ^ (r1 & 7)) * 8);
    const u16* Vsrc0 = Vtp + (size_t)bh * 64 * L + (size_t)r0 * L + ((c ^ (r0 & 7)) * 8);
    const u16* Vsrc1 = Vtp + (size_t)bh * 64 * L + (size_t)r1 * L + ((c ^ (r1 & 7)) * 8);

    auto stage = [&](int k0, int buf) {
        gl_lds16(Ksrc0 + (size_t)k0 * 64, &Kl[buf][(w * 16) * 64]);
        gl_lds16(Ksrc1 + (size_t)k0 * 64, &Kl[buf][(w * 16 + 8) * 64]);
        gl_lds16(Vsrc0 + k0, &Vl[buf][(w * 16) * 64]);
        gl_lds16(Vsrc1 + k0, &Vl[buf][(w * 16 + 8) * 64]);
    };

    int addrA[4][2];
#pragma unroll
    for (int f = 0; f < 4; ++f) {
        int row = f * 16 + lq;
#pragma unroll
        for (int s = 0; s < 2; ++s) addrA[f][s] = row * 64 + (((s * 4 + lg) ^ (row & 7)) * 8);
    }
    // P fragment read addrs (row = w*16+lq, row&7 == lq&7)
    const int paddr0 = (w * 16 + lq) * 64 + ((lg ^ (lq & 7)) * 8);
    const int paddr1 = (w * 16 + lq) * 64 + (((4 + lg) ^ (lq & 7)) * 8);

    f32x4 oacc[4] = {};
    float lrow[4] = {0.f, 0.f, 0.f, 0.f};

    stage(0, 0);
    for (int kt = 0; kt < 16; ++kt) {
        const int cur = kt & 1;
        __syncthreads();
        if (kt + 1 < 16) stage((kt + 1) * 64, cur ^ 1);

        f32x4 sc4[4];
#pragma unroll
        for (int f = 0; f < 4; ++f) {
            f32x4 a = {};
            a = __builtin_amdgcn_mfma_f32_16x16x32_bf16(qa0, ld_frag(&Kl[cur][addrA[f][0]]), a, 0, 0, 0);
            a = __builtin_amdgcn_mfma_f32_16x16x32_bf16(qa1, ld_frag(&Kl[cur][addrA[f][1]]), a, 0, 0, 0);
            sc4[f] = a;
        }
#pragma unroll
        for (int f = 0; f < 4; ++f) {
            float bv = kb ? kb[kt * 64 + f * 16 + lq] : 0.f;
#pragma unroll
            for (int r = 0; r < 4; ++r) {
                float pv = __expf(sc4[f][r] + bv);
                lrow[r] += pv;
                const int prow = w * 16 + lg * 4 + r;
                Pl[prow * 64 + (((f * 2 + (lq >> 3)) ^ (prow & 7)) * 8) + (lq & 7)] = f2b(pv);
            }
        }
        bf16x8 pa0 = ld_frag(&Pl[paddr0]);
        bf16x8 pa1 = ld_frag(&Pl[paddr1]);
#pragma unroll
        for (int db = 0; db < 4; ++db) {
            oacc[db] = __builtin_amdgcn_mfma_f32_16x16x32_bf16(pa0, ld_frag(&Vl[cur][addrA[db][0]]), oacc[db], 0, 0, 0);
            oacc[db] = __builtin_amdgcn_mfma_f32_16x16x32_bf16(pa1, ld_frag(&Vl[cur][addrA[db][1]]), oacc[db], 0, 0, 0);
        }
    }
#pragma unroll
    for (int r = 0; r < 4; ++r) {
        float v = lrow[r];
#pragma unroll
        for (int msk = 8; msk >= 1; msk >>= 1) v += __shfl_xor(v, msk, 16);
        lrow[r] = v;
    }
#pragma unroll
    for (int db = 0; db < 4; ++db) {
#pragma unroll
        for (int r = 0; r < 4; ++r) {
            float denom = lrow[r];
            float v = (denom > 0.f) ? oacc[db][r] / denom : 0.f;
            O[((size_t)bz * L + q0 + w * 16 + lg * 4 + r) * 512 + h * 64 + db * 16 + lq] = f2b(v);
        }
    }
}

// ---------- host ----------
extern "C" void kernel_launch(void* const* d_in, const int* in_sizes, int n_in,
                              void* d_out, int out_size, void* d_ws, size_t ws_size,
                              hipStream_t stream) {
    const int M = 4096;
    const float* LL = (const float*)d_in[0];
    const float* LH = (const float*)d_in[1];
    const float* raw_tau = (const float*)d_in[2];
    auto F = [&](int i) { return (const float*)d_in[i]; };
    const int BIG = 1 << 28;

    char* p = (char*)d_ws;
    auto alloc = [&](size_t bytes) { void* r = (void*)p; p += (bytes + 255) & ~(size_t)255; return r; };
    const size_t MDf = (size_t)M * 512 * 4, MDb = (size_t)M * 512 * 2;
    float* ll_s_f = (float*)alloc(MDf);
    float* lh_s_f = (float*)alloc(MDf);
    u16* ll_s_b = (u16*)alloc(MDb);
    u16* lh_s_b = (u16*)alloc(MDb);
    u16* Qp = (u16*)alloc(2 * MDb);
    u16* Kp = (u16*)alloc(2 * MDb);
    u16* Vt = (u16*)alloc(2 * MDb);
    u16* Cxb = (u16*)alloc(2 * MDb);
    float* ll_o_f = (float*)alloc(MDf);
    u16* ll_o_b = (u16*)alloc(MDb);
    float* lh_o_f = (float*)alloc(MDf);
    u16* lh_o_b = (u16*)alloc(MDb);
    float* cr_o_f = (float*)alloc(MDf);
    float* ln_f_ll = (float*)alloc(MDf);
    float* ln_f_lh = (float*)alloc(MDf);
    u16* ln_b = (u16*)alloc(MDb);
    u16* hb = (u16*)alloc((size_t)M * 2048 * 2);
    float* yf_ll = (float*)alloc(MDf);
    float* yf_lh = (float*)alloc(MDf);
    float* kbias = (float*)alloc(4096 * 4);
    float* bqkv_ll = (float*)alloc(1536 * 4);
    float* bqkv_lh = (float*)alloc(1536 * 4);
    float* bkv_cr = (float*)alloc(1024 * 4);
    const size_t WDD = (size_t)262144;
    u16* wqkv_ll = (u16*)alloc(3 * WDD * 2);
    u16* wqkv_lh = (u16*)alloc(3 * WDD * 2);
    u16* wkv_cr = (u16*)alloc(2 * WDD * 2);
    u16* wq_cr = (u16*)alloc(WDD * 2);
    u16* wo_ll = (u16*)alloc(WDD * 2);
    u16* wo_lh = (u16*)alloc(WDD * 2);
    u16* wo_cr = (u16*)alloc(WDD * 2);
    u16* wm[4];
    for (int i = 0; i < 4; ++i) wm[i] = (u16*)alloc((size_t)1048576 * 2);

    const size_t SET = (size_t)4 * 8 * 1024 * 64;

    ConvArgs ca;
    ca.e[0] = {F(3), wqkv_ll, (int)WDD};
    ca.e[1] = {F(5), wqkv_ll + WDD, (int)WDD};
    ca.e[2] = {F(7), wqkv_ll + 2 * WDD, (int)WDD};
    ca.e[3] = {F(11), wqkv_lh, (int)WDD};
    ca.e[4] = {F(13), wqkv_lh + WDD, (int)WDD};
    ca.e[5] = {F(15), wqkv_lh + 2 * WDD, (int)WDD};
    ca.e[6] = {F(19), wq_cr, (int)WDD};
    ca.e[7] = {F(21), wkv_cr, (int)WDD};
    ca.e[8] = {F(23), wkv_cr + WDD, (int)WDD};
    ca.e[9] = {F(9), wo_ll, (int)WDD};
    ca.e[10] = {F(17), wo_lh, (int)WDD};
    ca.e[11] = {F(25), wo_cr, (int)WDD};
    ca.e[12] = {F(27), wm[0], 1048576};
    ca.e[13] = {F(29), wm[1], 1048576};
    ca.e[14] = {F(31), wm[2], 1048576};
    ca.e[15] = {F(33), wm[3], 1048576};
    k_conv<<<dim3(256, 16), 256, 0, stream>>>(ca);

    CpyArgs cp;
    cp.e[0] = {F(4), bqkv_ll};
    cp.e[1] = {F(6), bqkv_ll + 512};
    cp.e[2] = {F(8), bqkv_ll + 1024};
    cp.e[3] = {F(12), bqkv_lh};
    cp.e[4] = {F(14), bqkv_lh + 512};
    cp.e[5] = {F(16), bqkv_lh + 1024};
    cp.e[6] = {F(22), bkv_cr};
    cp.e[7] = {F(24), bkv_cr + 512};
    k_cpyf<<<dim3(2, 8), 256, 0, stream>>>(cp);

    k_tin<<<dim3(32, 16, 8), dim3(32, 8), 0, stream>>>(LL, LH, ll_s_f, ll_s_b, lh_s_f, lh_s_b);
    k_mask<<<dim3(1024), 256, 0, stream>>>(lh_s_f, raw_tau, kbias);

    auto gp = [&](const u16* A, const u16* W, const float* bias, int N, int K, int nwg) {
        GP g = {};
        g.A = A; g.W = W; g.bias = bias; g.N = N; g.K = K; g.nwg = nwg;
        g.kB = BIG; g.vB = BIG;
        return g;
    };

    // qkv pair (128x128, y selects ll/lh)
    {
        GP a = gp(ll_s_b, wqkv_ll, bqkv_ll, 1536, 512, 384);
        a.kB = 512; a.vB = 1024; a.Qp = Qp; a.Kp = Kp; a.Vt = Vt;
        GP b = gp(lh_s_b, wqkv_lh, bqkv_lh, 1536, 512, 384);
        b.kB = 512; b.vB = 1024; b.Qp = Qp + SET; b.Kp = Kp + SET; b.Vt = Vt + SET;
        k_gemm<128, 128, 0, 1><<<dim3(384, 2), 256, 0, stream>>>(a, b, M);
    }
    // merged self-attention (1024 blocks, XCD-chunked)
    k_attn<<<dim3(1024), 256, 0, stream>>>(Qp, Kp, Vt, Cxb, kbias, 1024);
    // wo pair
    {
        GP a = gp(Cxb, wo_ll, F(10), 512, 512, 512);
        a.Cf = ll_o_f; a.Cb = ll_o_b;
        GP b = gp(Cxb + SET, wo_lh, F(18), 512, 512, 512);
        b.Cf = lh_o_f; b.Cb = lh_o_b;
        k_gemm<64, 64, 0, 0><<<dim3(512, 2), 256, 0, stream>>>(a, b, M);
    }
    k_ln<<<dim3(1024), 256, 0, stream>>>(lh_s_f, lh_o_f, nullptr, F(37), F(38), ln_f_lh, ln_b);
    // mlp_lh_up
    {
        GP a = gp(ln_b, wm[2], F(32), 2048, 512, 512);
        a.Cb = hb;
        k_gemm<128, 128, 1, 0><<<dim3(512, 1), 256, 0, stream>>>(a, a, M);
    }
    // crQ + crKV pair (different nwg; early exit on orig)
    {
        GP a = gp(ll_o_b, wq_cr, F(20), 512, 512, 512);
        a.Qp = Qp;  // kB=vB=BIG -> all Q
        GP b = gp(lh_o_b, wkv_cr, bkv_cr, 1024, 512, 1024);
        b.kB = 0; b.vB = 512; b.Kp = Kp; b.Vt = Vt;
        k_gemm<64, 64, 0, 1><<<dim3(1024, 2), 256, 0, stream>>>(a, b, M);
    }
    // cross attention (512 blocks)
    k_attn<<<dim3(512), 256, 0, stream>>>(Qp, Kp, Vt, Cxb, nullptr, 512);
    // wo_cr + mlp_lh_down pair (different K)
    {
        GP a = gp(Cxb, wo_cr, F(26), 512, 512, 512);
        a.Cf = cr_o_f;
        GP b = gp(hb, wm[3], F(34), 512, 2048, 512);
        b.Cf = yf_lh; b.res = ln_f_lh;
        k_gemm<64, 64, 0, 0><<<dim3(512, 2), 256, 0, stream>>>(a, b, M);
    }
    k_ln<<<dim3(1024), 256, 0, stream>>>(ll_s_f, ll_o_f, cr_o_f, F(35), F(36), ln_f_ll, ln_b);
    // mlp_ll_up
    {
        GP a = gp(ln_b, wm[0], F(28), 2048, 512, 512);
        a.Cb = hb;
        k_gemm<128, 128, 1, 0><<<dim3(512, 1), 256, 0, stream>>>(a, a, M);
    }
    // mlp_ll_down
    {
        GP a = gp(hb, wm[1], F(30), 512, 2048, 512);
        a.Cf = yf_ll; a.res = ln_f_ll;
        k_gemm<64, 64, 0, 0><<<dim3(512, 1), 256, 0, stream>>>(a, a, M);
    }
    k_tout<<<dim3(32, 16, 8), dim3(32, 8), 0, stream>>>(yf_ll, yf_lh, (float*)d_out);
}

// Round 8
// 268.723 us; speedup vs baseline: 1.2585x; 1.0192x over previous
//
#include <hip/hip_runtime.h>
#include <hip/hip_bf16.h>
#include <stdint.h>

typedef unsigned short u16;
typedef __bf16 bf16_t;
typedef bf16_t bf16x8 __attribute__((ext_vector_type(8)));
typedef float f32x4 __attribute__((ext_vector_type(4)));

#define DEV static __device__ __forceinline__

// ---------- helpers ----------
DEV u16 f2b(float f) {
    __hip_bfloat16 h = __float2bfloat16(f);
    return __builtin_bit_cast(u16, h);
}

DEV bf16x8 ld_frag(const u16* p) {
    uint4 u = *reinterpret_cast<const uint4*>(p);
    return __builtin_bit_cast(bf16x8, u);
}

// exact-GELU via tanh identity (max abs err ~3e-4; margin is 0.07)
DEV float gelu(float v) {
    float y = 0.79788456080286536f * (v + 0.044715f * v * v * v);
    float e = __expf(-2.f * fabsf(y));
    float th = (1.f - e) / (1.f + e);
    th = copysignf(th, y);
    return 0.5f * v * (1.f + th);
}

DEV void gl_lds16(const u16* g, u16* l) {
    __builtin_amdgcn_global_load_lds(
        (const __attribute__((address_space(1))) void*)(uintptr_t)g,
        (__attribute__((address_space(3))) void*)(unsigned int)(uintptr_t)l,
        16, 0, 0);
}

// ---------- weight fp32 -> bf16 conversion ----------
struct ConvEnt { const float* s; u16* d; int n; };
struct ConvArgs { ConvEnt e[16]; };

__global__ __launch_bounds__(256) void k_conv(ConvArgs a) {
    const ConvEnt en = a.e[blockIdx.y];
    for (int i = (blockIdx.x * 256 + threadIdx.x) * 4; i < en.n; i += 256 * 256 * 4) {
        const float4 f = *reinterpret_cast<const float4*>(en.s + i);
        unsigned r0 = (unsigned)f2b(f.x) | ((unsigned)f2b(f.y) << 16);
        unsigned r1 = (unsigned)f2b(f.z) | ((unsigned)f2b(f.w) << 16);
        uint2 rr; rr.x = r0; rr.y = r1;
        *reinterpret_cast<uint2*>(en.d + i) = rr;
    }
}

// ---------- fused-bias concat ----------
struct CpyEnt { const float* s; float* d; };
struct CpyArgs { CpyEnt e[8]; };

__global__ __launch_bounds__(256) void k_cpyf(CpyArgs a) {
    const CpyEnt en = a.e[blockIdx.y];
    int i = blockIdx.x * 256 + threadIdx.x;
    en.d[i] = en.s[i];
}

// ---------- merged transpose in ----------
__global__ __launch_bounds__(256) void k_tin(const float* __restrict__ LL, const float* __restrict__ LH,
                                             float* __restrict__ llf, u16* __restrict__ llb,
                                             float* __restrict__ lhf, u16* __restrict__ lhb) {
    __shared__ float t[32][33];
    int z = blockIdx.z, b = z & 3;
    const float* in = (z < 4) ? LL : LH;
    float* of = (z < 4) ? llf : lhf;
    u16* ob = (z < 4) ? llb : lhb;
    int l0 = blockIdx.x * 32, d0 = blockIdx.y * 32;
    int tx = threadIdx.x, ty = threadIdx.y;
#pragma unroll
    for (int j = 0; j < 4; ++j) {
        int d = d0 + ty + j * 8;
        t[ty + j * 8][tx] = in[((size_t)b * 512 + d) * 1024 + l0 + tx];
    }
    __syncthreads();
#pragma unroll
    for (int j = 0; j < 4; ++j) {
        int l = l0 + ty + j * 8;
        float v = t[tx][ty + j * 8];
        size_t o = ((size_t)b * 1024 + l) * 512 + d0 + tx;
        of[o] = v;
        ob[o] = f2b(v);
    }
}

// ---------- merged transpose out ----------
__global__ __launch_bounds__(256) void k_tout(const float* __restrict__ y0, const float* __restrict__ y1,
                                              float* __restrict__ out) {
    __shared__ float t[32][33];
    int z = blockIdx.z, b = z & 3;
    const float* in = (z < 4) ? y0 : y1;
    float* o = out + ((z < 4) ? 0 : (size_t)4096 * 512);
    int l0 = blockIdx.x * 32, d0 = blockIdx.y * 32;
    int tx = threadIdx.x, ty = threadIdx.y;
#pragma unroll
    for (int j = 0; j < 4; ++j) {
        int l = l0 + ty + j * 8;
        t[ty + j * 8][tx] = in[((size_t)b * 1024 + l) * 512 + d0 + tx];
    }
    __syncthreads();
#pragma unroll
    for (int j = 0; j < 4; ++j) {
        int d = d0 + ty + j * 8;
        o[((size_t)b * 512 + d) * 1024 + l0 + tx] = t[tx][ty + j * 8];
    }
}

// ---------- energy mask ----------
__global__ __launch_bounds__(256) void k_mask(const float* __restrict__ lh_s,
                                              const float* __restrict__ raw_tau,
                                              float* __restrict__ kbias) {
    int row = blockIdx.x * 4 + (threadIdx.x >> 6);
    int lane = threadIdx.x & 63;
    const float* p = lh_s + (size_t)row * 512 + lane * 8;
    float s = 0.f;
#pragma unroll
    for (int j = 0; j < 8; ++j) s += fabsf(p[j]);
#pragma unroll
    for (int m = 32; m >= 1; m >>= 1) s += __shfl_xor(s, m, 64);
    float tau = 1.f / (1.f + expf(-raw_tau[0]));
    if (lane == 0) kbias[row] = (s * (1.f / 512.f) > tau) ? 0.f : -3.0e38f;
}

// ---------- LayerNorm ----------
__global__ __launch_bounds__(256) void k_ln(const float* __restrict__ a, const float* __restrict__ b,
                                            const float* __restrict__ c, const float* __restrict__ w,
                                            const float* __restrict__ bi,
                                            float* __restrict__ of, u16* __restrict__ ob) {
    int row = blockIdx.x * 4 + (threadIdx.x >> 6);
    int lane = threadIdx.x & 63;
    size_t base = (size_t)row * 512 + lane * 8;
    float x[8];
#pragma unroll
    for (int j = 0; j < 8; ++j) {
        float v = a[base + j] + b[base + j];
        if (c) v += c[base + j];
        x[j] = v;
    }
    float s = 0.f, s2 = 0.f;
#pragma unroll
    for (int j = 0; j < 8; ++j) { s += x[j]; s2 += x[j] * x[j]; }
#pragma unroll
    for (int m = 32; m >= 1; m >>= 1) { s += __shfl_xor(s, m, 64); s2 += __shfl_xor(s2, m, 64); }
    float mean = s * (1.f / 512.f);
    float var = s2 * (1.f / 512.f) - mean * mean;
    float rs = rsqrtf(var + 1e-5f);
#pragma unroll
    for (int j = 0; j < 8; ++j) {
        float y = (x[j] - mean) * rs * w[lane * 8 + j] + bi[lane * 8 + j];
        of[base + j] = y;
        ob[base + j] = f2b(y);
    }
}

// ---------- paired bf16 MFMA GEMM (blockIdx.y selects descriptor) ----------
struct GP {
    const u16* A; const u16* W; const float* bias; const float* res;
    float* Cf; u16* Cb; u16* Qp; u16* Kp; u16* Vt;
    int N, K, kB, vB, nwg;
};

template <int BM, int BN, int GELU_ACT, int PACK>
__global__ __launch_bounds__(256) void k_gemm(GP p0, GP p1, int M) {
    constexpr int BK = 64;
    __shared__ alignas(16) u16 Al[2][BM * BK];
    __shared__ alignas(16) u16 Wl[2][BN * BK];
    GP g = (blockIdx.y == 0) ? p0 : p1;
    const int orig = blockIdx.x;
    if (orig >= g.nwg) return;
    int bid;
    {
        const int xcd = orig & 7, lin = orig >> 3;
        const int q = g.nwg >> 3, r = g.nwg & 7;
        bid = (xcd < r ? xcd * (q + 1) : r * (q + 1) + (xcd - r) * q) + lin;
    }
    const int K = g.K, N = g.N;
    const int nny = N / BN;
    const int m0 = (bid / nny) * BM, n0 = (bid % nny) * BN;

    const int t = threadIdx.x, w = t >> 6, l = t & 63;
    constexpr int FM = BM / 32, FN = BN / 32;
    const int wr = w >> 1, wc = w & 1;
    const int lq = l & 15, lg = l >> 4;
    f32x4 acc[FM][FN] = {};

    const int srow = l >> 3, schunk = l & 7;
    auto stage = [&](int kcol, int buf) {
#pragma unroll
        for (int i = 0; i < BM / 32; ++i) {
            const int row = i * 32 + w * 8 + srow;
            gl_lds16(g.A + (size_t)(m0 + row) * K + kcol + ((schunk ^ (row & 7)) * 8),
                     &Al[buf][(i * 32 + w * 8) * BK]);
        }
#pragma unroll
        for (int i = 0; i < BN / 32; ++i) {
            const int row = i * 32 + w * 8 + srow;
            gl_lds16(g.W + (size_t)(n0 + row) * K + kcol + ((schunk ^ (row & 7)) * 8),
                     &Wl[buf][(i * 32 + w * 8) * BK]);
        }
    };

    stage(0, 0);
    const int KT = K / BK;
    for (int kt = 0; kt < KT; ++kt) {
        const int cur = kt & 1;
        __syncthreads();
        if (kt + 1 < KT) stage((kt + 1) * BK, cur ^ 1);
#pragma unroll
        for (int s = 0; s < 2; ++s) {
            bf16x8 af[FM], bw[FN];
#pragma unroll
            for (int i = 0; i < FM; ++i) {
                const int row = wr * (BM / 2) + i * 16 + lq;
                af[i] = ld_frag(&Al[cur][row * BK + (((s * 4 + lg) ^ (row & 7)) * 8)]);
            }
#pragma unroll
            for (int j = 0; j < FN; ++j) {
                const int row = wc * (BN / 2) + j * 16 + lq;
                bw[j] = ld_frag(&Wl[cur][row * BK + (((s * 4 + lg) ^ (row & 7)) * 8)]);
            }
#pragma unroll
            for (int i = 0; i < FM; ++i)
#pragma unroll
                for (int j = 0; j < FN; ++j)
                    acc[i][j] = __builtin_amdgcn_mfma_f32_16x16x32_bf16(af[i], bw[j], acc[i][j], 0, 0, 0);
        }
    }

    if (PACK && n0 >= g.vB) {
        u16* T = (u16*)Al;
        constexpr int CH = BM / 8, CMASK = CH - 1, SH = (CH == 16) ? 4 : 3;
        __syncthreads();
#pragma unroll
        for (int i = 0; i < FM; ++i) {
#pragma unroll
            for (int j = 0; j < FN; ++j) {
                const int ni = wc * (BN / 2) + j * 16 + lq;
                const float bn = g.bias[n0 + ni];
#pragma unroll
                for (int r2 = 0; r2 < 4; ++r2) {
                    const int mi = wr * (BM / 2) + i * 16 + lg * 4 + r2;
                    T[ni * BM + (((mi >> 3) ^ (ni & CMASK)) * 8) + (mi & 7)] = f2b(acc[i][j][r2] + bn);
                }
            }
        }
        __syncthreads();
        const int bb = m0 >> 10, mloc = m0 & 1023;
        const int mc = t & CMASK, nib = t >> SH;
        constexpr int RPP = 256 / CH;
#pragma unroll
        for (int p2 = 0; p2 < BN / RPP; ++p2) {
            const int ni = nib + p2 * RPP;
            uint4 u = *reinterpret_cast<const uint4*>(&T[ni * BM + ((mc ^ (ni & CMASK)) * 8)]);
            const int d = n0 - g.vB + ni;
            *reinterpret_cast<uint4*>(
                &g.Vt[((size_t)(bb * 8 + (d >> 6)) * 64 + (d & 63)) * 1024 + mloc + mc * 8]) = u;
        }
        return;
    }

#pragma unroll
    for (int i = 0; i < FM; ++i) {
#pragma unroll
        for (int j = 0; j < FN; ++j) {
            const int n = n0 + wc * (BN / 2) + j * 16 + lq;
            const float bn = g.bias[n];
#pragma unroll
            for (int r2 = 0; r2 < 4; ++r2) {
                const int m = m0 + wr * (BM / 2) + i * 16 + lg * 4 + r2;
                float v = acc[i][j][r2] + bn;
                if (GELU_ACT) v = gelu(v);
                if (PACK) {
                    const int bb = m >> 10, ll_ = m & 1023;
                    if (n >= g.kB) {
                        const int d = n - g.kB;
                        g.Kp[((size_t)(bb * 8 + (d >> 6)) * 1024 + ll_) * 64 + (d & 63)] = f2b(v);
                    } else {
                        g.Qp[((size_t)(bb * 8 + (n >> 6)) * 1024 + ll_) * 64 + (n & 63)] = f2b(v * 0.125f);
                    }
                } else {
                    size_t o = (size_t)m * N + n;
                    if (g.res) v += g.res[o];
                    if (g.Cf) g.Cf[o] = v;
                    if (g.Cb) g.Cb[o] = f2b(v);
                }
            }
        }
    }
}

// ---------- flash attention: QBLK=128 (4 waves x 32 q-rows), 48KB LDS ----------
// Two Q A-frags share every K/V B-frag read -> halved LDS traffic per q-row.
__global__ __launch_bounds__(256) void k_attn(const u16* __restrict__ Qp, const u16* __restrict__ Kp,
                                              const u16* __restrict__ Vtp, u16* __restrict__ O,
                                              const float* __restrict__ kbias, int nwg) {
    constexpr int L = 1024;
    __shared__ alignas(16) u16 Kl[2][64 * 64];
    __shared__ alignas(16) u16 Vl[2][64 * 64];
    __shared__ alignas(16) u16 Pl[128 * 64];
    const int t = threadIdx.x, w = t >> 6, l = t & 63;
    const int bid = ((int)blockIdx.x & 7) * (nwg >> 3) + ((int)blockIdx.x >> 3);
    const int bh = bid >> 3, q0 = (bid & 7) * 128;
    const int bz = bh >> 3, h = bh & 7;
    const int lq = l & 15, lg = l >> 4;
    const float* kb = (kbias != nullptr && bz >= 4) ? (kbias + (size_t)(bz - 4) * L) : nullptr;

    bf16x8 qa[2][2];
#pragma unroll
    for (int i = 0; i < 2; ++i) {
        const u16* qp = Qp + ((size_t)bh * L + q0 + w * 32 + i * 16 + lq) * 64 + lg * 8;
        qa[i][0] = ld_frag(qp);
        qa[i][1] = ld_frag(qp + 32);
    }

    const int r0 = w * 16 + (l >> 3), r1 = r0 + 8, c = l & 7;
    const u16* Ksrc0 = Kp + (size_t)bh * L * 64 + (size_t)r0 * 64 + ((c ^ (r0 & 7)) * 8);
    const u16* Ksrc1 = Kp + (size_t)bh * L * 64 + (size_t)r1 * 64 + ((c ^ (r1 & 7)) * 8);
    const u16* Vsrc0 = Vtp + (size_t)bh * 64 * L + (size_t)r0 * L + ((c ^ (r0 & 7)) * 8);
    const u16* Vsrc1 = Vtp + (size_t)bh * 64 * L + (size_t)r1 * L + ((c ^ (r1 & 7)) * 8);

    auto stage = [&](int k0, int buf) {
        gl_lds16(Ksrc0 + (size_t)k0 * 64, &Kl[buf][(w * 16) * 64]);
        gl_lds16(Ksrc1 + (size_t)k0 * 64, &Kl[buf][(w * 16 + 8) * 64]);
        gl_lds16(Vsrc0 + k0, &Vl[buf][(w * 16) * 64]);
        gl_lds16(Vsrc1 + k0, &Vl[buf][(w * 16 + 8) * 64]);
    };

    int addrA[4][2];
#pragma unroll
    for (int f = 0; f < 4; ++f) {
        int row = f * 16 + lq;
#pragma unroll
        for (int s = 0; s < 2; ++s) addrA[f][s] = row * 64 + (((s * 4 + lg) ^ (row & 7)) * 8);
    }
    int paddr[2][2], pwbase[2];
#pragma unroll
    for (int i = 0; i < 2; ++i) {
        const int prow = w * 32 + i * 16 + lq;
#pragma unroll
        for (int s = 0; s < 2; ++s) paddr[i][s] = prow * 64 + (((s * 4 + lg) ^ (prow & 7)) * 8);
        pwbase[i] = w * 32 + i * 16 + lg * 4;
    }

    f32x4 oacc[2][4] = {};
    float lrow[2][4] = {};

    stage(0, 0);
    for (int kt = 0; kt < 16; ++kt) {
        const int cur = kt & 1;
        __syncthreads();
        if (kt + 1 < 16) stage((kt + 1) * 64, cur ^ 1);

        f32x4 sc[2][4];
#pragma unroll
        for (int f = 0; f < 4; ++f) {
            bf16x8 k0 = ld_frag(&Kl[cur][addrA[f][0]]);
            bf16x8 k1 = ld_frag(&Kl[cur][addrA[f][1]]);
#pragma unroll
            for (int i = 0; i < 2; ++i) {
                f32x4 a = {};
                a = __builtin_amdgcn_mfma_f32_16x16x32_bf16(qa[i][0], k0, a, 0, 0, 0);
                a = __builtin_amdgcn_mfma_f32_16x16x32_bf16(qa[i][1], k1, a, 0, 0, 0);
                sc[i][f] = a;
            }
        }
#pragma unroll
        for (int f = 0; f < 4; ++f) {
            float bv = kb ? kb[kt * 64 + f * 16 + lq] : 0.f;
#pragma unroll
            for (int i = 0; i < 2; ++i) {
#pragma unroll
                for (int r = 0; r < 4; ++r) {
                    float pv = __expf(sc[i][f][r] + bv);
                    lrow[i][r] += pv;
                    const int prow = pwbase[i] + r;
                    Pl[prow * 64 + (((f * 2 + (lq >> 3)) ^ (prow & 7)) * 8) + (lq & 7)] = f2b(pv);
                }
            }
        }
        bf16x8 pa[2][2];
#pragma unroll
        for (int i = 0; i < 2; ++i) {
            pa[i][0] = ld_frag(&Pl[paddr[i][0]]);
            pa[i][1] = ld_frag(&Pl[paddr[i][1]]);
        }
#pragma unroll
        for (int db = 0; db < 4; ++db) {
            bf16x8 v0 = ld_frag(&Vl[cur][addrA[db][0]]);
            bf16x8 v1 = ld_frag(&Vl[cur][addrA[db][1]]);
#pragma unroll
            for (int i = 0; i < 2; ++i) {
                oacc[i][db] = __builtin_amdgcn_mfma_f32_16x16x32_bf16(pa[i][0], v0, oacc[i][db], 0, 0, 0);
                oacc[i][db] = __builtin_amdgcn_mfma_f32_16x16x32_bf16(pa[i][1], v1, oacc[i][db], 0, 0, 0);
            }
        }
    }
#pragma unroll
    for (int i = 0; i < 2; ++i)
#pragma unroll
        for (int r = 0; r < 4; ++r) {
            float v = lrow[i][r];
#pragma unroll
            for (int msk = 8; msk >= 1; msk >>= 1) v += __shfl_xor(v, msk, 16);
            lrow[i][r] = v;
        }
#pragma unroll
    for (int i = 0; i < 2; ++i) {
#pragma unroll
        for (int db = 0; db < 4; ++db) {
#pragma unroll
            for (int r = 0; r < 4; ++r) {
                float denom = lrow[i][r];
                float v = (denom > 0.f) ? oacc[i][db][r] / denom : 0.f;
                O[((size_t)bz * L + q0 + w * 32 + i * 16 + lg * 4 + r) * 512 + h * 64 + db * 16 + lq] = f2b(v);
            }
        }
    }
}

// ---------- host ----------
extern "C" void kernel_launch(void* const* d_in, const int* in_sizes, int n_in,
                              void* d_out, int out_size, void* d_ws, size_t ws_size,
                              hipStream_t stream) {
    const int M = 4096;
    const float* LL = (const float*)d_in[0];
    const float* LH = (const float*)d_in[1];
    const float* raw_tau = (const float*)d_in[2];
    auto F = [&](int i) { return (const float*)d_in[i]; };
    const int BIG = 1 << 28;

    char* p = (char*)d_ws;
    auto alloc = [&](size_t bytes) { void* r = (void*)p; p += (bytes + 255) & ~(size_t)255; return r; };
    const size_t MDf = (size_t)M * 512 * 4, MDb = (size_t)M * 512 * 2;
    float* ll_s_f = (float*)alloc(MDf);
    float* lh_s_f = (float*)alloc(MDf);
    u16* ll_s_b = (u16*)alloc(MDb);
    u16* lh_s_b = (u16*)alloc(MDb);
    u16* Qp = (u16*)alloc(2 * MDb);
    u16* Kp = (u16*)alloc(2 * MDb);
    u16* Vt = (u16*)alloc(2 * MDb);
    u16* Cxb = (u16*)alloc(2 * MDb);
    float* ll_o_f = (float*)alloc(MDf);
    u16* ll_o_b = (u16*)alloc(MDb);
    float* lh_o_f = (float*)alloc(MDf);
    u16* lh_o_b = (u16*)alloc(MDb);
    float* cr_o_f = (float*)alloc(MDf);
    float* ln_f_ll = (float*)alloc(MDf);
    float* ln_f_lh = (float*)alloc(MDf);
    u16* ln_b = (u16*)alloc(MDb);
    u16* hb = (u16*)alloc((size_t)M * 2048 * 2);
    float* yf_ll = (float*)alloc(MDf);
    float* yf_lh = (float*)alloc(MDf);
    float* kbias = (float*)alloc(4096 * 4);
    float* bqkv_ll = (float*)alloc(1536 * 4);
    float* bqkv_lh = (float*)alloc(1536 * 4);
    float* bkv_cr = (float*)alloc(1024 * 4);
    const size_t WDD = (size_t)262144;
    u16* wqkv_ll = (u16*)alloc(3 * WDD * 2);
    u16* wqkv_lh = (u16*)alloc(3 * WDD * 2);
    u16* wkv_cr = (u16*)alloc(2 * WDD * 2);
    u16* wq_cr = (u16*)alloc(WDD * 2);
    u16* wo_ll = (u16*)alloc(WDD * 2);
    u16* wo_lh = (u16*)alloc(WDD * 2);
    u16* wo_cr = (u16*)alloc(WDD * 2);
    u16* wm[4];
    for (int i = 0; i < 4; ++i) wm[i] = (u16*)alloc((size_t)1048576 * 2);

    const size_t SET = (size_t)4 * 8 * 1024 * 64;

    ConvArgs ca;
    ca.e[0] = {F(3), wqkv_ll, (int)WDD};
    ca.e[1] = {F(5), wqkv_ll + WDD, (int)WDD};
    ca.e[2] = {F(7), wqkv_ll + 2 * WDD, (int)WDD};
    ca.e[3] = {F(11), wqkv_lh, (int)WDD};
    ca.e[4] = {F(13), wqkv_lh + WDD, (int)WDD};
    ca.e[5] = {F(15), wqkv_lh + 2 * WDD, (int)WDD};
    ca.e[6] = {F(19), wq_cr, (int)WDD};
    ca.e[7] = {F(21), wkv_cr, (int)WDD};
    ca.e[8] = {F(23), wkv_cr + WDD, (int)WDD};
    ca.e[9] = {F(9), wo_ll, (int)WDD};
    ca.e[10] = {F(17), wo_lh, (int)WDD};
    ca.e[11] = {F(25), wo_cr, (int)WDD};
    ca.e[12] = {F(27), wm[0], 1048576};
    ca.e[13] = {F(29), wm[1], 1048576};
    ca.e[14] = {F(31), wm[2], 1048576};
    ca.e[15] = {F(33), wm[3], 1048576};
    k_conv<<<dim3(256, 16), 256, 0, stream>>>(ca);

    CpyArgs cp;
    cp.e[0] = {F(4), bqkv_ll};
    cp.e[1] = {F(6), bqkv_ll + 512};
    cp.e[2] = {F(8), bqkv_ll + 1024};
    cp.e[3] = {F(12), bqkv_lh};
    cp.e[4] = {F(14), bqkv_lh + 512};
    cp.e[5] = {F(16), bqkv_lh + 1024};
    cp.e[6] = {F(22), bkv_cr};
    cp.e[7] = {F(24), bkv_cr + 512};
    k_cpyf<<<dim3(2, 8), 256, 0, stream>>>(cp);

    k_tin<<<dim3(32, 16, 8), dim3(32, 8), 0, stream>>>(LL, LH, ll_s_f, ll_s_b, lh_s_f, lh_s_b);
    k_mask<<<dim3(1024), 256, 0, stream>>>(lh_s_f, raw_tau, kbias);

    auto gp = [&](const u16* A, const u16* W, const float* bias, int N, int K, int nwg) {
        GP g = {};
        g.A = A; g.W = W; g.bias = bias; g.N = N; g.K = K; g.nwg = nwg;
        g.kB = BIG; g.vB = BIG;
        return g;
    };

    // qkv pair (128x128, y selects ll/lh)
    {
        GP a = gp(ll_s_b, wqkv_ll, bqkv_ll, 1536, 512, 384);
        a.kB = 512; a.vB = 1024; a.Qp = Qp; a.Kp = Kp; a.Vt = Vt;
        GP b = gp(lh_s_b, wqkv_lh, bqkv_lh, 1536, 512, 384);
        b.kB = 512; b.vB = 1024; b.Qp = Qp + SET; b.Kp = Kp + SET; b.Vt = Vt + SET;
        k_gemm<128, 128, 0, 1><<<dim3(384, 2), 256, 0, stream>>>(a, b, M);
    }
    // merged self-attention (512 blocks: 64 bh x 8 q-tiles of 128)
    k_attn<<<dim3(512), 256, 0, stream>>>(Qp, Kp, Vt, Cxb, kbias, 512);
    // wo pair
    {
        GP a = gp(Cxb, wo_ll, F(10), 512, 512, 512);
        a.Cf = ll_o_f; a.Cb = ll_o_b;
        GP b = gp(Cxb + SET, wo_lh, F(18), 512, 512, 512);
        b.Cf = lh_o_f; b.Cb = lh_o_b;
        k_gemm<64, 64, 0, 0><<<dim3(512, 2), 256, 0, stream>>>(a, b, M);
    }
    k_ln<<<dim3(1024), 256, 0, stream>>>(lh_s_f, lh_o_f, nullptr, F(37), F(38), ln_f_lh, ln_b);
    // mlp_lh_up
    {
        GP a = gp(ln_b, wm[2], F(32), 2048, 512, 512);
        a.Cb = hb;
        k_gemm<128, 128, 1, 0><<<dim3(512, 1), 256, 0, stream>>>(a, a, M);
    }
    // crQ + crKV pair
    {
        GP a = gp(ll_o_b, wq_cr, F(20), 512, 512, 512);
        a.Qp = Qp;
        GP b = gp(lh_o_b, wkv_cr, bkv_cr, 1024, 512, 1024);
        b.kB = 0; b.vB = 512; b.Kp = Kp; b.Vt = Vt;
        k_gemm<64, 64, 0, 1><<<dim3(1024, 2), 256, 0, stream>>>(a, b, M);
    }
    // cross attention (256 blocks)
    k_attn<<<dim3(256), 256, 0, stream>>>(Qp, Kp, Vt, Cxb, nullptr, 256);
    // wo_cr + mlp_lh_down pair
    {
        GP a = gp(Cxb, wo_cr, F(26), 512, 512, 512);
        a.Cf = cr_o_f;
        GP b = gp(hb, wm[3], F(34), 512, 2048, 512);
        b.Cf = yf_lh; b.res = ln_f_lh;
        k_gemm<64, 64, 0, 0><<<dim3(512, 2), 256, 0, stream>>>(a, b, M);
    }
    k_ln<<<dim3(1024), 256, 0, stream>>>(ll_s_f, ll_o_f, cr_o_f, F(35), F(36), ln_f_ll, ln_b);
    // mlp_ll_up
    {
        GP a = gp(ln_b, wm[0], F(28), 2048, 512, 512);
        a.Cb = hb;
        k_gemm<128, 128, 1, 0><<<dim3(512, 1), 256, 0, stream>>>(a, a, M);
    }
    // mlp_ll_down
    {
        GP a = gp(hb, wm[1], F(30), 512, 2048, 512);
        a.Cf = yf_ll; a.res = ln_f_ll;
        k_gemm<64, 64, 0, 0><<<dim3(512, 1), 256, 0, stream>>>(a, a, M);
    }
    k_tout<<<dim3(32, 16, 8), dim3(32, 8), 0, stream>>>(yf_ll, yf_lh, (float*)d_out);
}